// Round 1
// 1923.685 us; speedup vs baseline: 1.8628x; 1.8628x over previous
//
#include <hip/hip_runtime.h>

typedef unsigned short u16;
typedef __bf16 bf8 __attribute__((ext_vector_type(8)));
typedef float f32x4 __attribute__((ext_vector_type(4)));

// ---------- bf16 helpers for INTERMEDIATE storage (inputs/outputs are fp32) ----------
__device__ __forceinline__ float b2f(u16 u){
  union { unsigned int i; float f; } z; z.i = ((unsigned int)u) << 16; return z.f;
}
__device__ __forceinline__ u16 f2b(float f){
  union { float f; unsigned int i; } z; z.f = f;
  unsigned int lsb = (z.i >> 16) & 1u;
  return (u16)((z.i + 0x7fffu + lsb) >> 16);
}

#define EPSf 1e-5f

// ---------------------------------------------------------------------------
// K0a: fold BN1/BN2 into 3x3 weights (1x1 into center tap) -> W3B bf16 in
// MFMA A-frag layout [ct4][c8 8][tap9][q4][oc64][j8], + BIASL fp32.
// grid 2304 x 256
// ---------------------------------------------------------------------------
__global__ __launch_bounds__(256) void k_prep_w3(
    const float* __restrict__ w1, const float* __restrict__ w2,
    const float* __restrict__ g1, const float* __restrict__ b1,
    const float* __restrict__ m1, const float* __restrict__ v1,
    const float* __restrict__ g2, const float* __restrict__ b2,
    const float* __restrict__ m2, const float* __restrict__ v2,
    u16* __restrict__ W3B, float* __restrict__ BIASL){
  int e = blockIdx.x*256 + threadIdx.x;       // < 589824
  int c = e / 2304; int r = e - c*2304; int s = r / 9; int tap = r - s*9;
  float inv1 = g1[c] * rsqrtf(v1[c] + EPSf);
  float val = w1[e] * inv1;
  if (tap == 4){
    float inv2 = g2[c] * rsqrtf(v2[c] + EPSf);
    val += w2[c*256 + s] * inv2;
  }
  int ct = c >> 6, oc_l = c & 63;
  int c8 = s >> 5, q = (s >> 3) & 3, j = s & 7;
  W3B[((((ct*8 + c8)*9 + tap)*4 + q)*64 + oc_l)*8 + j] = f2b(val);
  if (e < 256){
    float i1 = g1[e] * rsqrtf(v1[e] + EPSf);
    float i2 = g2[e] * rsqrtf(v2[e] + EPSf);
    BIASL[e] = (b1[e] - m1[e]*i1) + (b2[e] - m2[e]*i2);
  }
}

// ---------------------------------------------------------------------------
// K0b: fold BNp into pointwise weights
// ---------------------------------------------------------------------------
__global__ __launch_bounds__(256) void k_prep_pw(
    const float* __restrict__ wpw,
    const float* __restrict__ gp, const float* __restrict__ bp,
    const float* __restrict__ mp, const float* __restrict__ vp,
    float* __restrict__ WPW, float* __restrict__ BIASPW){
  __shared__ float invp[256], betap[256];
  int t = threadIdx.x;
  float iv = gp[t] * rsqrtf(vp[t] + EPSf);
  invp[t] = iv; betap[t] = bp[t] - mp[t]*iv;
  __syncthreads();
  float bias = 0.f;
  for (int c = 0; c < 256; ++c){
    float w = wpw[t*256 + c];
    WPW[t*256 + c] = w * invp[c];
    bias += w * betap[c];
  }
  BIASPW[t] = bias;
}

// ---------------------------------------------------------------------------
// K0d: convert wqkv fp32 [768][256] -> bf16 same layout (= [mat3][hd16][outd16][cin256]).
// This is directly the MFMA B-fragment feed: lane reads 8 contiguous cin for outd=lane&15.
// grid 768 x 256
// ---------------------------------------------------------------------------
__global__ __launch_bounds__(256) void k_prep_wqkv(
    const float* __restrict__ wqkv, u16* __restrict__ WQB){
  int i = blockIdx.x*256 + threadIdx.x;      // < 196608
  WQB[i] = f2b(wqkv[i]);
}

// ---------------------------------------------------------------------------
// K0c: transpose y (fp32 NCHW) -> YT bf16 NHWC [b][h][w][cin].
// one block per (b,h). grid 512 x 256.
// ---------------------------------------------------------------------------
__global__ __launch_bounds__(256) void k_prep_yT(
    const float* __restrict__ y, u16* __restrict__ YT){
  __shared__ u16 ls[32*264];            // [cin32][w 256(+8)]
  int bh = blockIdx.x; int b = bh >> 8; int h = bh & 255;
  int t = threadIdx.x;
  for (int c8 = 0; c8 < 8; ++c8){
    if (c8) __syncthreads();
    for (int ci = 0; ci < 32; ++ci)
      ls[ci*264 + t] = f2b(y[(b*256 + c8*32 + ci)*65536 + h*256 + t]);
    __syncthreads();
    int tq = t & 3, wl = t >> 2;
    for (int wb = 0; wb < 4; ++wb){
      int w = wb*64 + wl;
      u16 tmp[8];
      #pragma unroll
      for (int j = 0; j < 8; ++j) tmp[j] = ls[(tq*8 + j)*264 + w];
      *(uint4*)(YT + ((b*256 + h)*256 + w)*256 + c8*32 + tq*8) = *(const uint4*)tmp;
    }
  }
}

// ---------------------------------------------------------------------------
// K1: local conv3x3 as implicit GEMM via MFMA 16x16x32 bf16.
// block = 64 oc x 64 px (one output row segment), 4 waves, grid 8192 x 256.
// K loop: 8 cin-chunks x 9 taps. LDS: wt 36864B + yt 16320B = 53184B.
// ---------------------------------------------------------------------------
__global__ __launch_bounds__(256) void k_local(
    const u16* __restrict__ YT, const u16* __restrict__ W3B,
    const float* __restrict__ BIASL, u16* __restrict__ LOCB){
  __shared__ __align__(16) u16 wt[18432];   // [tap9][q4][oc64][j8]
  __shared__ __align__(16) u16 yt[8160];    // [row3][col68 (stride 40)][cin32]
  int bi = blockIdx.x;
  int ct = bi & 3, wsg = (bi>>2)&3, h = (bi>>4)&255, b = bi>>12;
  int w0 = wsg << 6;
  int t = threadIdx.x;
  int wv = t >> 6, lane = t & 63, pxl = lane & 15, quad = lane >> 4;
  f32x4 acc0 = {0.f,0.f,0.f,0.f}, acc1 = acc0, acc2 = acc0, acc3 = acc0;
  const u16* wsrc = W3B + ct*8*18432;
  for (int c8 = 0; c8 < 8; ++c8){
    if (c8) __syncthreads();
    // stage W3B chunk: contiguous 36864 B
    const uint4* gs = (const uint4*)(wsrc + c8*18432);
    uint4* wd = (uint4*)wt;
    #pragma unroll
    for (int i = 0; i < 9; ++i) wd[i*256 + t] = gs[i*256 + t];
    // stage y tile: 3 rows x 66 cols x 32 cin (zero pad OOB)
    for (int e = t; e < 792; e += 256){
      int rc = e >> 2, q = e & 3;
      int row = rc / 66, col = rc - row*66;
      int gh = h - 1 + row, gw = w0 - 1 + col;
      uint4 v = make_uint4(0u,0u,0u,0u);
      if (((unsigned)gh < 256u) && ((unsigned)gw < 256u))
        v = *(const uint4*)(YT + ((b*256 + gh)*256 + gw)*256 + c8*32 + q*8);
      *(uint4*)(yt + (row*68 + col)*40 + q*8) = v;
    }
    __syncthreads();
    #pragma unroll
    for (int tap = 0; tap < 9; ++tap){
      int dr = tap / 3, dc = tap - dr*3;
      bf8 a = *(const bf8*)(wt + ((tap*4 + quad)*64 + wv*16 + pxl)*8);
      int boff = (dr*68 + dc + pxl)*40 + quad*8;
      acc0 = __builtin_amdgcn_mfma_f32_16x16x32_bf16(a, *(const bf8*)(yt + boff       ), acc0, 0,0,0);
      acc1 = __builtin_amdgcn_mfma_f32_16x16x32_bf16(a, *(const bf8*)(yt + boff +  640), acc1, 0,0,0);
      acc2 = __builtin_amdgcn_mfma_f32_16x16x32_bf16(a, *(const bf8*)(yt + boff + 1280), acc2, 0,0,0);
      acc3 = __builtin_amdgcn_mfma_f32_16x16x32_bf16(a, *(const bf8*)(yt + boff + 1920), acc3, 0,0,0);
    }
  }
  int ocb = ct*64 + wv*16 + quad*4;
  float bs[4];
  #pragma unroll
  for (int r = 0; r < 4; ++r) bs[r] = BIASL[ocb + r];
  u16* ob = LOCB + (b*256 + ocb)*65536 + h*256 + w0 + pxl;
  #pragma unroll
  for (int r = 0; r < 4; ++r){
    ob[r*65536 +  0] = f2b(acc0[r] + bs[r]);
    ob[r*65536 + 16] = f2b(acc1[r] + bs[r]);
    ob[r*65536 + 32] = f2b(acc2[r] + bs[r]);
    ob[r*65536 + 48] = f2b(acc3[r] + bs[r]);
  }
}

// ---------------------------------------------------------------------------
// K2: fused qkv 1x1 conv (MFMA) + window attention (VALU) -> ATT (bf16, NCHW)
// block = one 8x8 window, 4 waves. grid 2048 x 256.
// Per head: wave wv computes token-tile wv of Q,K,V via 24 mfma_16x16x32_bf16
// (A = xt LDS tile, B = WQB global bf16, L2-resident 393KB), scatters C-frags
// to f32 LDS q/k/v buffers; then VALU QK^T (+rpb), all-thread softmax, VALU PV.
// LDS = 65024 B -> 2 blocks/CU.
// ---------------------------------------------------------------------------
__global__ __launch_bounds__(256) void k_attn(
    const float* __restrict__ x, const u16* __restrict__ WQB,
    const float* __restrict__ rpb, u16* __restrict__ ATT){
  __shared__ __align__(16) u16 xt[64*264];     // [tok][cin], 33792 B
  __shared__ float qbuf[64*17];                // [tok][d], 4352 B
  __shared__ __align__(16) float kbuf[64*20];  // [tok][d], 5120 B (float4 rows)
  __shared__ __align__(16) float vbuf[64*20];  // [tok][d], 5120 B
  __shared__ float sm[64*65];                  // scores/probs, 16640 B
  int t = threadIdx.x;
  int bi = blockIdx.x;
  int b = bi >> 10; int wi = bi & 1023;
  int h0 = (wi >> 5) << 3; int w0 = (wi & 31) << 3;
  // stage x tile -> bf16 [tok64][cin256] stride 264
  for (int e = t; e < 16384; e += 256){
    int c = e >> 6; int tk = e & 63;
    int r = tk >> 3, cc = tk & 7;
    xt[tk*264 + c] = f2b(x[((b*256 + c)*256 + (h0+r))*256 + (w0+cc)]);
  }
  int wv = t >> 6, lane = t & 63, pxl = lane & 15, quad = lane >> 4;
  int tok = t & 63, grp = t >> 6;
  int ri = tok >> 3, ci = tok & 7;
  __syncthreads();
  for (int hd = 0; hd < 16; ++hd){
    // ---- MFMA qkv: wave wv owns token-tile wv (tokens wv*16..wv*16+15)
    {
      const u16* abase = xt + (wv*16 + pxl)*264 + quad*8;
      #pragma unroll
      for (int mat = 0; mat < 3; ++mat){
        const u16* bbase = WQB + (((mat<<8) + (hd<<4) + pxl)<<8) + (quad<<3);
        f32x4 acc = {0.f,0.f,0.f,0.f};
        #pragma unroll
        for (int kc = 0; kc < 8; ++kc){
          bf8 a  = *(const bf8*)(abase + kc*32);
          bf8 bf = *(const bf8*)(bbase + kc*32);
          acc = __builtin_amdgcn_mfma_f32_16x16x32_bf16(a, bf, acc, 0,0,0);
        }
        float s = (mat == 0) ? 0.25f : 1.f;
        float* obuf = (mat==0) ? qbuf : (mat==1) ? kbuf : vbuf;
        int stride  = (mat==0) ? 17 : 20;
        int rbase = wv*16 + quad*4;
        #pragma unroll
        for (int r = 0; r < 4; ++r)
          obuf[(rbase + r)*stride + pxl] = acc[r]*s;
      }
    }
    __syncthreads();
    // ---- QK^T + relative position bias  (thread = (tok, grp); j = grp*16+jj)
    {
      float qv[16];
      #pragma unroll
      for (int d = 0; d < 16; ++d) qv[d] = qbuf[tok*17 + d];
      #pragma unroll 2
      for (int jj = 0; jj < 16; ++jj){
        int j = (grp<<4) + jj;
        const float* kr = &kbuf[j*20];
        float4 k0 = *(const float4*)(kr);
        float4 k1 = *(const float4*)(kr+4);
        float4 k2 = *(const float4*)(kr+8);
        float4 k3 = *(const float4*)(kr+12);
        float d0 = qv[0]*k0.x + qv[1]*k0.y + qv[2]*k0.z + qv[3]*k0.w
                 + qv[4]*k1.x + qv[5]*k1.y + qv[6]*k1.z + qv[7]*k1.w
                 + qv[8]*k2.x + qv[9]*k2.y + qv[10]*k2.z + qv[11]*k2.w
                 + qv[12]*k3.x + qv[13]*k3.y + qv[14]*k3.z + qv[15]*k3.w;
        int rj = j >> 3, cj = j & 7;
        int idx = (ri - rj + 7)*15 + (ci - cj + 7);
        sm[tok*65 + j] = d0 + rpb[(idx<<4) + hd];
      }
    }
    __syncthreads();
    // ---- softmax: 4 lanes per row (row = t>>2), shfl_xor reduce within quad
    {
      float* row = &sm[(t>>2)*65 + ((t&3)<<4)];
      float mx = -1e30f;
      #pragma unroll
      for (int jj = 0; jj < 16; ++jj) mx = fmaxf(mx, row[jj]);
      mx = fmaxf(mx, __shfl_xor(mx, 1));
      mx = fmaxf(mx, __shfl_xor(mx, 2));
      float ev[16]; float sum = 0.f;
      #pragma unroll
      for (int jj = 0; jj < 16; ++jj){ ev[jj] = __expf(row[jj]-mx); sum += ev[jj]; }
      sum += __shfl_xor(sum, 1);
      sum += __shfl_xor(sum, 2);
      float inv = 1.f / sum;
      #pragma unroll
      for (int jj = 0; jj < 16; ++jj) row[jj] = ev[jj]*inv;
    }
    __syncthreads();
    // ---- PV: thread (tok, grp) -> channels hd*16 + grp*4 + 0..3
    {
      float o0=0.f,o1=0.f,o2=0.f,o3=0.f;
      const float* arow = &sm[tok*65];
      const float* vcol = &vbuf[grp<<2];
      #pragma unroll 8
      for (int j = 0; j < 64; ++j){
        float a = arow[j];
        float4 vr = *(const float4*)(vcol + j*20);
        o0 += a*vr.x; o1 += a*vr.y; o2 += a*vr.z; o3 += a*vr.w;
      }
      int base = ((b*256 + (hd<<4) + (grp<<2))*256 + (h0 + ri))*256 + (w0 + ci);
      ATT[base]           = f2b(o0);
      ATT[base +   65536] = f2b(o1);
      ATT[base + 2*65536] = f2b(o2);
      ATT[base + 3*65536] = f2b(o3);
    }
    __syncthreads();
  }
}

// ---------------------------------------------------------------------------
// K3: comb = avgpool_v(attn) + avgpool_h(attn) + local, in-place into LOCB.
// ---------------------------------------------------------------------------
__global__ __launch_bounds__(256) void k_comb(
    const u16* __restrict__ ATT, u16* __restrict__ LOCB){
  __shared__ float pt[39][256];
  int bi = blockIdx.x;
  int rb = bi & 7; int c = (bi>>3)&255; int b = bi>>11;
  int h0 = rb<<5;
  int t = threadIdx.x;
  const u16* P = ATT + (b*256 + c)*65536;
  for (int e = t; e < 9984; e += 256){
    int r = e >> 8; int cc = e & 255;
    int g = h0 - 3 + r;
    float v = 0.f;
    if ((unsigned)g < 256u) v = b2f(P[(g<<8) + cc]);
    else if (g == 256) v = b2f(P[(254<<8) + cc]);
    pt[r][cc] = v;
  }
  __syncthreads();
  int w = t;
  float colsum = 0.f;
  #pragma unroll
  for (int k = 0; k < 8; ++k) colsum += pt[k][w];
  u16* O = LOCB + (b*256 + c)*65536 + (h0<<8);
  for (int hr = 0; hr < 32; ++hr){
    const float* prow = pt[hr + 3];
    float s = 0.f;
    #pragma unroll
    for (int j = 0; j < 8; ++j){
      int cc = w - 3 + j;
      float v = 0.f;
      if ((unsigned)cc < 256u) v = prow[cc];
      else if (cc == 256) v = prow[254];
      s += v;
    }
    float res = (colsum + s)*0.125f + b2f(O[(hr<<8) + w]);
    O[(hr<<8) + w] = f2b(res);
    if (hr < 31) colsum += pt[hr+8][w] - pt[hr][w];
  }
}

// ---------------------------------------------------------------------------
// K4: 8x8 depthwise conv, reflect(0,1) pad + zero conv-pad 3 -> DWO (bf16)
// ---------------------------------------------------------------------------
__global__ __launch_bounds__(256) void k_dw(
    const u16* __restrict__ COMB, const float* __restrict__ wdw,
    u16* __restrict__ DWO){
  __shared__ float pt[39][264];
  __shared__ float wl[64];
  int bi = blockIdx.x;
  int rb = bi & 7; int c = (bi>>3)&255; int b = bi>>11;
  int h0 = rb<<5;
  int t = threadIdx.x;
  const u16* P = COMB + (b*256 + c)*65536;
  for (int e = t; e < 10296; e += 256){
    int r = e / 264; int cc = e - r*264;
    int g = h0 - 3 + r;
    int gc = cc - 3;
    int gr  = (g  == 256) ? 254 : g;
    int gcc = (gc == 256) ? 254 : gc;
    float v = 0.f;
    if (((unsigned)gr < 256u) && ((unsigned)gcc < 256u))
      v = b2f(P[(gr<<8) + gcc]);
    pt[r][cc] = v;
  }
  if (t < 64) wl[t] = wdw[(c<<6) + t];
  __syncthreads();
  int w = t;
  for (int hr = 0; hr < 32; ++hr){
    float acc = 0.f;
    #pragma unroll
    for (int i = 0; i < 8; ++i){
      const float* prow = &pt[hr + i][w];
      #pragma unroll
      for (int j = 0; j < 8; ++j)
        acc += wl[(i<<3) + j] * prow[j];
    }
    DWO[(b*256 + c)*65536 + ((h0+hr)<<8) + w] = f2b(acc);
  }
}

// ---------------------------------------------------------------------------
// K5: pointwise 1x1 (BNp folded) -> OUT fp32
// ---------------------------------------------------------------------------
__global__ __launch_bounds__(256) void k_pw(
    const u16* __restrict__ DW, const float* __restrict__ WPW,
    const float* __restrict__ BIASPW, float* __restrict__ OUT){
  __shared__ float wt[16][68];
  __shared__ float dt[16][65];
  int bi = blockIdx.x;
  int ot = bi & 3; int ptile = bi >> 2;
  int t = threadIdx.x;
  int p = t & 63, cg16 = (t>>6)<<4;
  int n0 = ptile << 6;
  int b = n0 >> 16; int pix0 = n0 & 65535;
  const u16* Dbase = DW + b*16777216 + pix0;
  float acc[16];
  #pragma unroll
  for (int i=0;i<16;++i) acc[i] = 0.f;
  for (int k0 = 0; k0 < 256; k0 += 16){
    for (int e = t; e < 1024; e += 256){
      int kk = e >> 6; int pp = e & 63;
      dt[kk][pp] = b2f(Dbase[(k0+kk)*65536 + pp]);
    }
    for (int e = t; e < 1024; e += 256){
      int oc_l = e >> 4; int k = e & 15;
      wt[k][oc_l] = WPW[((ot<<6) + oc_l)*256 + k0 + k];
    }
    __syncthreads();
    #pragma unroll
    for (int k = 0; k < 16; ++k){
      float dv = dt[k][p];
      const float* wr = &wt[k][cg16];
      float4 w0v = *(const float4*)(wr);
      float4 w1v = *(const float4*)(wr+4);
      float4 w2v = *(const float4*)(wr+8);
      float4 w3v = *(const float4*)(wr+12);
      acc[0]  += dv*w0v.x; acc[1]  += dv*w0v.y; acc[2]  += dv*w0v.z; acc[3]  += dv*w0v.w;
      acc[4]  += dv*w1v.x; acc[5]  += dv*w1v.y; acc[6]  += dv*w1v.z; acc[7]  += dv*w1v.w;
      acc[8]  += dv*w2v.x; acc[9]  += dv*w2v.y; acc[10] += dv*w2v.z; acc[11] += dv*w2v.w;
      acc[12] += dv*w3v.x; acc[13] += dv*w3v.y; acc[14] += dv*w3v.z; acc[15] += dv*w3v.w;
    }
    __syncthreads();
  }
  int oc0 = (ot<<6) + cg16;
  int ob = b*16777216 + pix0 + p;
  #pragma unroll
  for (int i=0;i<16;++i)
    OUT[ob + (oc0+i)*65536] = acc[i] + BIASPW[oc0+i];
}

// ---------------------------------------------------------------------------
extern "C" void kernel_launch(void* const* d_in, const int* in_sizes, int n_in,
                              void* d_out, int out_size, void* d_ws, size_t ws_size,
                              hipStream_t stream){
  const float* x    = (const float*)d_in[0];
  const float* y    = (const float*)d_in[1];
  const float* wqkv = (const float*)d_in[2];
  const float* wl1  = (const float*)d_in[3];
  const float* g1   = (const float*)d_in[4];
  const float* b1   = (const float*)d_in[5];
  const float* m1   = (const float*)d_in[6];
  const float* v1   = (const float*)d_in[7];
  const float* wl2  = (const float*)d_in[8];
  const float* g2   = (const float*)d_in[9];
  const float* b2   = (const float*)d_in[10];
  const float* m2   = (const float*)d_in[11];
  const float* v2   = (const float*)d_in[12];
  const float* wdw  = (const float*)d_in[13];
  const float* gp   = (const float*)d_in[14];
  const float* bp   = (const float*)d_in[15];
  const float* mp   = (const float*)d_in[16];
  const float* vp   = (const float*)d_in[17];
  const float* wpw  = (const float*)d_in[18];
  const float* rpb  = (const float*)d_in[19];

  float* BIASL  = (float*)d_ws;                    // 256 f32
  float* WPW    = BIASL + 256;                     // 65536 f32
  float* BIASPW = WPW + 65536;                     // 256 f32
  u16* W3B   = (u16*)(BIASPW + 256);               // 589824 bf16 (MFMA layout)
  u16* WQB   = W3B + 589824;                       // 196608 bf16 qkv weights
  u16* YTATT = WQB + 196608;                       // 33.5M bf16: YT, then ATT, then DWO
  u16* LOCB  = YTATT + 33554432;                   // 33.5M bf16: local -> comb in place
  float* OUT = (float*)d_out;

  k_prep_w3<<<2304, 256, 0, stream>>>(wl1, wl2, g1, b1, m1, v1, g2, b2, m2, v2, W3B, BIASL);
  k_prep_pw<<<1, 256, 0, stream>>>(wpw, gp, bp, mp, vp, WPW, BIASPW);
  k_prep_wqkv<<<768, 256, 0, stream>>>(wqkv, WQB);
  k_prep_yT<<<512, 256, 0, stream>>>(y, YTATT);
  k_local<<<8192, 256, 0, stream>>>(YTATT, W3B, BIASL, LOCB);
  k_attn<<<2048, 256, 0, stream>>>(x, WQB, rpb, YTATT);     // ATT overwrites dead YT
  k_comb<<<4096, 256, 0, stream>>>(YTATT, LOCB);
  k_dw<<<4096, 256, 0, stream>>>(LOCB, wdw, YTATT);         // DWO overwrites dead ATT
  k_pw<<<8192, 256, 0, stream>>>(YTATT, WPW, BIASPW, OUT);
}

// Round 2
// 1831.095 us; speedup vs baseline: 1.9570x; 1.0506x over previous
//
#include <hip/hip_runtime.h>

typedef unsigned short u16;
typedef __bf16 bf8 __attribute__((ext_vector_type(8)));
typedef float f32x4 __attribute__((ext_vector_type(4)));

// ---------- bf16 helpers for INTERMEDIATE storage (inputs/outputs are fp32) ----------
__device__ __forceinline__ float b2f(u16 u){
  union { unsigned int i; float f; } z; z.i = ((unsigned int)u) << 16; return z.f;
}
__device__ __forceinline__ u16 f2b(float f){
  union { float f; unsigned int i; } z; z.f = f;
  unsigned int lsb = (z.i >> 16) & 1u;
  return (u16)((z.i + 0x7fffu + lsb) >> 16);
}

#define EPSf 1e-5f

// ---------------------------------------------------------------------------
// K0a: fold BN1/BN2 into 3x3 weights (1x1 into center tap) -> W3B bf16 in
// MFMA A-frag layout [ct4][c8 8][tap9][q4][oc64][j8], + BIASL fp32.
// grid 2304 x 256
// ---------------------------------------------------------------------------
__global__ __launch_bounds__(256) void k_prep_w3(
    const float* __restrict__ w1, const float* __restrict__ w2,
    const float* __restrict__ g1, const float* __restrict__ b1,
    const float* __restrict__ m1, const float* __restrict__ v1,
    const float* __restrict__ g2, const float* __restrict__ b2,
    const float* __restrict__ m2, const float* __restrict__ v2,
    u16* __restrict__ W3B, float* __restrict__ BIASL){
  int e = blockIdx.x*256 + threadIdx.x;       // < 589824
  int c = e / 2304; int r = e - c*2304; int s = r / 9; int tap = r - s*9;
  float inv1 = g1[c] * rsqrtf(v1[c] + EPSf);
  float val = w1[e] * inv1;
  if (tap == 4){
    float inv2 = g2[c] * rsqrtf(v2[c] + EPSf);
    val += w2[c*256 + s] * inv2;
  }
  int ct = c >> 6, oc_l = c & 63;
  int c8 = s >> 5, q = (s >> 3) & 3, j = s & 7;
  W3B[((((ct*8 + c8)*9 + tap)*4 + q)*64 + oc_l)*8 + j] = f2b(val);
  if (e < 256){
    float i1 = g1[e] * rsqrtf(v1[e] + EPSf);
    float i2 = g2[e] * rsqrtf(v2[e] + EPSf);
    BIASL[e] = (b1[e] - m1[e]*i1) + (b2[e] - m2[e]*i2);
  }
}

// ---------------------------------------------------------------------------
// K0b: fold BNp into pointwise weights
// ---------------------------------------------------------------------------
__global__ __launch_bounds__(256) void k_prep_pw(
    const float* __restrict__ wpw,
    const float* __restrict__ gp, const float* __restrict__ bp,
    const float* __restrict__ mp, const float* __restrict__ vp,
    float* __restrict__ WPW, float* __restrict__ BIASPW){
  __shared__ float invp[256], betap[256];
  int t = threadIdx.x;
  float iv = gp[t] * rsqrtf(vp[t] + EPSf);
  invp[t] = iv; betap[t] = bp[t] - mp[t]*iv;
  __syncthreads();
  float bias = 0.f;
  for (int c = 0; c < 256; ++c){
    float w = wpw[t*256 + c];
    WPW[t*256 + c] = w * invp[c];
    bias += w * betap[c];
  }
  BIASPW[t] = bias;
}

// ---------------------------------------------------------------------------
// K0d: convert wqkv fp32 [768][256] -> bf16 same layout (= [mat3][hd16][outd16][cin256]).
// Directly the MFMA B-fragment feed: lane reads 8 contiguous cin for outd=lane&15.
// grid 768 x 256
// ---------------------------------------------------------------------------
__global__ __launch_bounds__(256) void k_prep_wqkv(
    const float* __restrict__ wqkv, u16* __restrict__ WQB){
  int i = blockIdx.x*256 + threadIdx.x;      // < 196608
  WQB[i] = f2b(wqkv[i]);
}

// ---------------------------------------------------------------------------
// K0c: transpose y (fp32 NCHW) -> YT bf16 NHWC [b][h][w][cin].
// one block per (b,h). grid 512 x 256.
// ---------------------------------------------------------------------------
__global__ __launch_bounds__(256) void k_prep_yT(
    const float* __restrict__ y, u16* __restrict__ YT){
  __shared__ u16 ls[32*264];            // [cin32][w 256(+8)]
  int bh = blockIdx.x; int b = bh >> 8; int h = bh & 255;
  int t = threadIdx.x;
  for (int c8 = 0; c8 < 8; ++c8){
    if (c8) __syncthreads();
    for (int ci = 0; ci < 32; ++ci)
      ls[ci*264 + t] = f2b(y[(b*256 + c8*32 + ci)*65536 + h*256 + t]);
    __syncthreads();
    int tq = t & 3, wl = t >> 2;
    for (int wb = 0; wb < 4; ++wb){
      int w = wb*64 + wl;
      u16 tmp[8];
      #pragma unroll
      for (int j = 0; j < 8; ++j) tmp[j] = ls[(tq*8 + j)*264 + w];
      *(uint4*)(YT + ((b*256 + h)*256 + w)*256 + c8*32 + tq*8) = *(const uint4*)tmp;
    }
  }
}

// ---------------------------------------------------------------------------
// K1: local conv3x3 as implicit GEMM via MFMA 16x16x32 bf16.
// block = 64 oc x 64 px (one output row segment), 4 waves, grid 8192 x 256.
// K loop: 8 cin-chunks x 9 taps. LDS: wt 36864B + yt 16320B = 53184B.
// ---------------------------------------------------------------------------
__global__ __launch_bounds__(256) void k_local(
    const u16* __restrict__ YT, const u16* __restrict__ W3B,
    const float* __restrict__ BIASL, u16* __restrict__ LOCB){
  __shared__ __align__(16) u16 wt[18432];   // [tap9][q4][oc64][j8]
  __shared__ __align__(16) u16 yt[8160];    // [row3][col68 (stride 40)][cin32]
  int bi = blockIdx.x;
  int ct = bi & 3, wsg = (bi>>2)&3, h = (bi>>4)&255, b = bi>>12;
  int w0 = wsg << 6;
  int t = threadIdx.x;
  int wv = t >> 6, lane = t & 63, pxl = lane & 15, quad = lane >> 4;
  f32x4 acc0 = {0.f,0.f,0.f,0.f}, acc1 = acc0, acc2 = acc0, acc3 = acc0;
  const u16* wsrc = W3B + ct*8*18432;
  for (int c8 = 0; c8 < 8; ++c8){
    if (c8) __syncthreads();
    // stage W3B chunk: contiguous 36864 B
    const uint4* gs = (const uint4*)(wsrc + c8*18432);
    uint4* wd = (uint4*)wt;
    #pragma unroll
    for (int i = 0; i < 9; ++i) wd[i*256 + t] = gs[i*256 + t];
    // stage y tile: 3 rows x 66 cols x 32 cin (zero pad OOB)
    for (int e = t; e < 792; e += 256){
      int rc = e >> 2, q = e & 3;
      int row = rc / 66, col = rc - row*66;
      int gh = h - 1 + row, gw = w0 - 1 + col;
      uint4 v = make_uint4(0u,0u,0u,0u);
      if (((unsigned)gh < 256u) && ((unsigned)gw < 256u))
        v = *(const uint4*)(YT + ((b*256 + gh)*256 + gw)*256 + c8*32 + q*8);
      *(uint4*)(yt + (row*68 + col)*40 + q*8) = v;
    }
    __syncthreads();
    #pragma unroll
    for (int tap = 0; tap < 9; ++tap){
      int dr = tap / 3, dc = tap - dr*3;
      bf8 a = *(const bf8*)(wt + ((tap*4 + quad)*64 + wv*16 + pxl)*8);
      int boff = (dr*68 + dc + pxl)*40 + quad*8;
      acc0 = __builtin_amdgcn_mfma_f32_16x16x32_bf16(a, *(const bf8*)(yt + boff       ), acc0, 0,0,0);
      acc1 = __builtin_amdgcn_mfma_f32_16x16x32_bf16(a, *(const bf8*)(yt + boff +  640), acc1, 0,0,0);
      acc2 = __builtin_amdgcn_mfma_f32_16x16x32_bf16(a, *(const bf8*)(yt + boff + 1280), acc2, 0,0,0);
      acc3 = __builtin_amdgcn_mfma_f32_16x16x32_bf16(a, *(const bf8*)(yt + boff + 1920), acc3, 0,0,0);
    }
  }
  int ocb = ct*64 + wv*16 + quad*4;
  float bs[4];
  #pragma unroll
  for (int r = 0; r < 4; ++r) bs[r] = BIASL[ocb + r];
  u16* ob = LOCB + (b*256 + ocb)*65536 + h*256 + w0 + pxl;
  #pragma unroll
  for (int r = 0; r < 4; ++r){
    ob[r*65536 +  0] = f2b(acc0[r] + bs[r]);
    ob[r*65536 + 16] = f2b(acc1[r] + bs[r]);
    ob[r*65536 + 32] = f2b(acc2[r] + bs[r]);
    ob[r*65536 + 48] = f2b(acc3[r] + bs[r]);
  }
}

// ---------------------------------------------------------------------------
// K2: fully-MFMA window attention.
// Per block: one 8x8 window, 4 waves. Per head: qkv proj (A-frags hoisted in
// regs, B from L2), QK^T MFMA (d=16 zero-padded to K=32), in-register softmax
// (shfl_xor row reduce), PV MFMA. LDS: xt 33792B unioned with dbuf qkv + P
// = 34304 B -> 4 blocks/CU. 2 barriers/head.
// ---------------------------------------------------------------------------
__global__ __launch_bounds__(256, 4) void k_attn(
    const float* __restrict__ x, const u16* __restrict__ WQB,
    const float* __restrict__ rpb, u16* __restrict__ ATT){
  __shared__ __align__(16) unsigned char smem[34304];
  // layout: xt = u16[64][264] @0 (33792B), dead after prologue. Then:
  //   set s (s=0,1) @ s*12544: qb u16[64][40] @+0, kb u16[64][40] @+5120,
  //                            vbt u16[16][72] @+10240 (2304B)
  //   pb u16[64][72] @25088 (9216B)   total 34304
  u16* xt = (u16*)smem;
  int t = threadIdx.x;
  int bi = blockIdx.x;
  int b = bi >> 10; int wi = bi & 1023;
  int h0 = (wi >> 5) << 3; int w0 = (wi & 31) << 3;
  int wv = t >> 6, lane = t & 63, pxl = lane & 15, quad = lane >> 4;

  // ---- stage x -> xt bf16 [tok][cin] stride 264
  for (int e = t; e < 16384; e += 256){
    int c = e >> 6; int tk = e & 63;
    int r = tk >> 3, cc = tk & 7;
    xt[tk*264 + c] = f2b(x[((b*256 + c)*256 + (h0+r))*256 + (w0+cc)]);
  }
  __syncthreads();
  // ---- hoist A-frags: af[kc] = X[tok = wv*16+pxl][cin = kc*32+quad*8 ..+7]
  bf8 af[8];
  #pragma unroll
  for (int kc = 0; kc < 8; ++kc)
    af[kc] = *(const bf8*)(xt + (wv*16 + pxl)*264 + kc*32 + quad*8);
  // ---- precompute rpb offsets (x16 prescaled), packed 2/reg
  // tile nt (cols j = nt*16+pxl), reg r (rows = wv*16+quad*4+r)
  unsigned int bp[8];
  {
    int row0 = wv*16 + quad*4;
    #pragma unroll
    for (int nt = 0; nt < 4; ++nt){
      int j = nt*16 + pxl; int rj = j >> 3, cj = j & 7;
      unsigned int v01, v23;
      {
        int row = row0;     int i0 = (((row>>3) - rj + 7)*15 + ((row&7) - cj + 7))<<4;
        row = row0 + 1;     int i1 = (((row>>3) - rj + 7)*15 + ((row&7) - cj + 7))<<4;
        v01 = (unsigned)i0 | ((unsigned)i1 << 16);
        row = row0 + 2;     int i2 = (((row>>3) - rj + 7)*15 + ((row&7) - cj + 7))<<4;
        row = row0 + 3;     int i3 = (((row>>3) - rj + 7)*15 + ((row&7) - cj + 7))<<4;
        v23 = (unsigned)i2 | ((unsigned)i3 << 16);
      }
      bp[nt*2]   = v01;
      bp[nt*2+1] = v23;
    }
  }
  __syncthreads();                      // xt now dead
  // ---- zero filler cols d=16..31 of qb,kb (both sets) for K=32 zero-pad
  for (int e = t; e < 2048; e += 256){
    int cp = e & 7; int row = (e>>3) & 63; int s2 = (e>>9) & 1; int qk = e >> 10;
    *(unsigned int*)(smem + s2*12544 + qk*5120 + row*80 + 32 + cp*4) = 0u;
  }

  for (int hd = 0; hd < 16; ++hd){
    int sb = (hd & 1)*12544;
    u16* qb  = (u16*)(smem + sb);
    u16* kb  = (u16*)(smem + sb + 5120);
    u16* vbt = (u16*)(smem + sb + 10240);
    u16* pb  = (u16*)(smem + 25088);
    int tok0 = wv*16 + quad*4;
    // ---- (a) qkv projection MFMA: A from regs, B from global (L2)
    #pragma unroll
    for (int mat = 0; mat < 3; ++mat){
      const u16* bbase = WQB + (((mat<<8) + (hd<<4) + pxl)<<8) + (quad<<3);
      f32x4 acc = {0.f,0.f,0.f,0.f};
      #pragma unroll
      for (int kc = 0; kc < 8; ++kc){
        bf8 bf = *(const bf8*)(bbase + kc*32);
        acc = __builtin_amdgcn_mfma_f32_16x16x32_bf16(af[kc], bf, acc, 0,0,0);
      }
      if (mat == 0){
        #pragma unroll
        for (int r = 0; r < 4; ++r) qb[(tok0 + r)*40 + pxl] = f2b(acc[r]*0.25f);
      } else if (mat == 1){
        #pragma unroll
        for (int r = 0; r < 4; ++r) kb[(tok0 + r)*40 + pxl] = f2b(acc[r]);
      } else {
        u16 tmp[4];
        #pragma unroll
        for (int r = 0; r < 4; ++r) tmp[r] = f2b(acc[r]);
        *(ushort4*)(vbt + pxl*72 + tok0) = *(const ushort4*)tmp;  // [d][tok]
      }
    }
    __syncthreads();
    // ---- (c) QK^T MFMA + bias + in-register softmax -> pb (bf16 A-frag layout)
    {
      bf8 aq = *(const bf8*)(qb + (wv*16 + pxl)*40 + quad*8);
      f32x4 sc[4];
      #pragma unroll
      for (int nt = 0; nt < 4; ++nt){
        bf8 bk = *(const bf8*)(kb + (nt*16 + pxl)*40 + quad*8);
        f32x4 z = {0.f,0.f,0.f,0.f};
        sc[nt] = __builtin_amdgcn_mfma_f32_16x16x32_bf16(aq, bk, z, 0,0,0);
      }
      #pragma unroll
      for (int nt = 0; nt < 4; ++nt){
        sc[nt][0] += rpb[(bp[nt*2]   & 0xffffu) + hd];
        sc[nt][1] += rpb[(bp[nt*2]   >> 16)     + hd];
        sc[nt][2] += rpb[(bp[nt*2+1] & 0xffffu) + hd];
        sc[nt][3] += rpb[(bp[nt*2+1] >> 16)     + hd];
      }
      #pragma unroll
      for (int r = 0; r < 4; ++r){
        float mx = fmaxf(fmaxf(sc[0][r], sc[1][r]), fmaxf(sc[2][r], sc[3][r]));
        mx = fmaxf(mx, __shfl_xor(mx, 1));
        mx = fmaxf(mx, __shfl_xor(mx, 2));
        mx = fmaxf(mx, __shfl_xor(mx, 4));
        mx = fmaxf(mx, __shfl_xor(mx, 8));
        float e0 = __expf(sc[0][r]-mx), e1 = __expf(sc[1][r]-mx);
        float e2 = __expf(sc[2][r]-mx), e3 = __expf(sc[3][r]-mx);
        float sum = (e0+e1) + (e2+e3);
        sum += __shfl_xor(sum, 1);
        sum += __shfl_xor(sum, 2);
        sum += __shfl_xor(sum, 4);
        sum += __shfl_xor(sum, 8);
        float inv = 1.f / sum;
        sc[0][r] = e0*inv; sc[1][r] = e1*inv; sc[2][r] = e2*inv; sc[3][r] = e3*inv;
      }
      #pragma unroll
      for (int nt = 0; nt < 4; ++nt)
        #pragma unroll
        for (int r = 0; r < 4; ++r)
          pb[(tok0 + r)*72 + nt*16 + pxl] = f2b(sc[nt][r]);
    }
    __syncthreads();
    // ---- (e) PV MFMA -> global ATT (packed ushort4 stores)
    {
      const u16* prow = pb + (wv*16 + pxl)*72 + quad*8;
      const u16* vrow = vbt + pxl*72 + quad*8;
      bf8 pa0 = *(const bf8*)(prow);
      bf8 pa1 = *(const bf8*)(prow + 32);
      bf8 vb0 = *(const bf8*)(vrow);
      bf8 vb1 = *(const bf8*)(vrow + 32);
      f32x4 o = {0.f,0.f,0.f,0.f};
      o = __builtin_amdgcn_mfma_f32_16x16x32_bf16(pa0, vb0, o, 0,0,0);
      o = __builtin_amdgcn_mfma_f32_16x16x32_bf16(pa1, vb1, o, 0,0,0);
      u16 tmp[4];
      #pragma unroll
      for (int r = 0; r < 4; ++r) tmp[r] = f2b(o[r]);
      u16* dst = ATT + (b*256 + (hd<<4) + pxl)*65536
                     + (h0 + wv*2 + (quad>>1))*256 + w0 + (quad&1)*4;
      *(ushort4*)dst = *(const ushort4*)tmp;
    }
    __syncthreads();
  }
}

// ---------------------------------------------------------------------------
// K3: comb = avgpool_v(attn) + avgpool_h(attn) + local, in-place into LOCB.
// ---------------------------------------------------------------------------
__global__ __launch_bounds__(256) void k_comb(
    const u16* __restrict__ ATT, u16* __restrict__ LOCB){
  __shared__ float pt[39][256];
  int bi = blockIdx.x;
  int rb = bi & 7; int c = (bi>>3)&255; int b = bi>>11;
  int h0 = rb<<5;
  int t = threadIdx.x;
  const u16* P = ATT + (b*256 + c)*65536;
  for (int e = t; e < 9984; e += 256){
    int r = e >> 8; int cc = e & 255;
    int g = h0 - 3 + r;
    float v = 0.f;
    if ((unsigned)g < 256u) v = b2f(P[(g<<8) + cc]);
    else if (g == 256) v = b2f(P[(254<<8) + cc]);
    pt[r][cc] = v;
  }
  __syncthreads();
  int w = t;
  float colsum = 0.f;
  #pragma unroll
  for (int k = 0; k < 8; ++k) colsum += pt[k][w];
  u16* O = LOCB + (b*256 + c)*65536 + (h0<<8);
  for (int hr = 0; hr < 32; ++hr){
    const float* prow = pt[hr + 3];
    float s = 0.f;
    #pragma unroll
    for (int j = 0; j < 8; ++j){
      int cc = w - 3 + j;
      float v = 0.f;
      if ((unsigned)cc < 256u) v = prow[cc];
      else if (cc == 256) v = prow[254];
      s += v;
    }
    float res = (colsum + s)*0.125f + b2f(O[(hr<<8) + w]);
    O[(hr<<8) + w] = f2b(res);
    if (hr < 31) colsum += pt[hr+8][w] - pt[hr][w];
  }
}

// ---------------------------------------------------------------------------
// K4: 8x8 depthwise conv, reflect(0,1) pad + zero conv-pad 3 -> DWO (bf16)
// ---------------------------------------------------------------------------
__global__ __launch_bounds__(256) void k_dw(
    const u16* __restrict__ COMB, const float* __restrict__ wdw,
    u16* __restrict__ DWO){
  __shared__ float pt[39][264];
  __shared__ float wl[64];
  int bi = blockIdx.x;
  int rb = bi & 7; int c = (bi>>3)&255; int b = bi>>11;
  int h0 = rb<<5;
  int t = threadIdx.x;
  const u16* P = COMB + (b*256 + c)*65536;
  for (int e = t; e < 10296; e += 256){
    int r = e / 264; int cc = e - r*264;
    int g = h0 - 3 + r;
    int gc = cc - 3;
    int gr  = (g  == 256) ? 254 : g;
    int gcc = (gc == 256) ? 254 : gc;
    float v = 0.f;
    if (((unsigned)gr < 256u) && ((unsigned)gcc < 256u))
      v = b2f(P[(gr<<8) + gcc]);
    pt[r][cc] = v;
  }
  if (t < 64) wl[t] = wdw[(c<<6) + t];
  __syncthreads();
  int w = t;
  for (int hr = 0; hr < 32; ++hr){
    float acc = 0.f;
    #pragma unroll
    for (int i = 0; i < 8; ++i){
      const float* prow = &pt[hr + i][w];
      #pragma unroll
      for (int j = 0; j < 8; ++j)
        acc += wl[(i<<3) + j] * prow[j];
    }
    DWO[(b*256 + c)*65536 + ((h0+hr)<<8) + w] = f2b(acc);
  }
}

// ---------------------------------------------------------------------------
// K5: pointwise 1x1 (BNp folded) -> OUT fp32
// ---------------------------------------------------------------------------
__global__ __launch_bounds__(256) void k_pw(
    const u16* __restrict__ DW, const float* __restrict__ WPW,
    const float* __restrict__ BIASPW, float* __restrict__ OUT){
  __shared__ float wt[16][68];
  __shared__ float dt[16][65];
  int bi = blockIdx.x;
  int ot = bi & 3; int ptile = bi >> 2;
  int t = threadIdx.x;
  int p = t & 63, cg16 = (t>>6)<<4;
  int n0 = ptile << 6;
  int b = n0 >> 16; int pix0 = n0 & 65535;
  const u16* Dbase = DW + b*16777216 + pix0;
  float acc[16];
  #pragma unroll
  for (int i=0;i<16;++i) acc[i] = 0.f;
  for (int k0 = 0; k0 < 256; k0 += 16){
    for (int e = t; e < 1024; e += 256){
      int kk = e >> 6; int pp = e & 63;
      dt[kk][pp] = b2f(Dbase[(k0+kk)*65536 + pp]);
    }
    for (int e = t; e < 1024; e += 256){
      int oc_l = e >> 4; int k = e & 15;
      wt[k][oc_l] = WPW[((ot<<6) + oc_l)*256 + k0 + k];
    }
    __syncthreads();
    #pragma unroll
    for (int k = 0; k < 16; ++k){
      float dv = dt[k][p];
      const float* wr = &wt[k][cg16];
      float4 w0v = *(const float4*)(wr);
      float4 w1v = *(const float4*)(wr+4);
      float4 w2v = *(const float4*)(wr+8);
      float4 w3v = *(const float4*)(wr+12);
      acc[0]  += dv*w0v.x; acc[1]  += dv*w0v.y; acc[2]  += dv*w0v.z; acc[3]  += dv*w0v.w;
      acc[4]  += dv*w1v.x; acc[5]  += dv*w1v.y; acc[6]  += dv*w1v.z; acc[7]  += dv*w1v.w;
      acc[8]  += dv*w2v.x; acc[9]  += dv*w2v.y; acc[10] += dv*w2v.z; acc[11] += dv*w2v.w;
      acc[12] += dv*w3v.x; acc[13] += dv*w3v.y; acc[14] += dv*w3v.z; acc[15] += dv*w3v.w;
    }
    __syncthreads();
  }
  int oc0 = (ot<<6) + cg16;
  int ob = b*16777216 + pix0 + p;
  #pragma unroll
  for (int i=0;i<16;++i)
    OUT[ob + (oc0+i)*65536] = acc[i] + BIASPW[oc0+i];
}

// ---------------------------------------------------------------------------
extern "C" void kernel_launch(void* const* d_in, const int* in_sizes, int n_in,
                              void* d_out, int out_size, void* d_ws, size_t ws_size,
                              hipStream_t stream){
  const float* x    = (const float*)d_in[0];
  const float* y    = (const float*)d_in[1];
  const float* wqkv = (const float*)d_in[2];
  const float* wl1  = (const float*)d_in[3];
  const float* g1   = (const float*)d_in[4];
  const float* b1   = (const float*)d_in[5];
  const float* m1   = (const float*)d_in[6];
  const float* v1   = (const float*)d_in[7];
  const float* wl2  = (const float*)d_in[8];
  const float* g2   = (const float*)d_in[9];
  const float* b2   = (const float*)d_in[10];
  const float* m2   = (const float*)d_in[11];
  const float* v2   = (const float*)d_in[12];
  const float* wdw  = (const float*)d_in[13];
  const float* gp   = (const float*)d_in[14];
  const float* bp   = (const float*)d_in[15];
  const float* mp   = (const float*)d_in[16];
  const float* vp   = (const float*)d_in[17];
  const float* wpw  = (const float*)d_in[18];
  const float* rpb  = (const float*)d_in[19];

  float* BIASL  = (float*)d_ws;                    // 256 f32
  float* WPW    = BIASL + 256;                     // 65536 f32
  float* BIASPW = WPW + 65536;                     // 256 f32
  u16* W3B   = (u16*)(BIASPW + 256);               // 589824 bf16 (MFMA layout)
  u16* WQB   = W3B + 589824;                       // 196608 bf16 qkv weights
  u16* YTATT = WQB + 196608;                       // 33.5M bf16: YT, then ATT, then DWO
  u16* LOCB  = YTATT + 33554432;                   // 33.5M bf16: local -> comb in place
  float* OUT = (float*)d_out;

  k_prep_w3<<<2304, 256, 0, stream>>>(wl1, wl2, g1, b1, m1, v1, g2, b2, m2, v2, W3B, BIASL);
  k_prep_pw<<<1, 256, 0, stream>>>(wpw, gp, bp, mp, vp, WPW, BIASPW);
  k_prep_wqkv<<<768, 256, 0, stream>>>(wqkv, WQB);
  k_prep_yT<<<512, 256, 0, stream>>>(y, YTATT);
  k_local<<<8192, 256, 0, stream>>>(YTATT, W3B, BIASL, LOCB);
  k_attn<<<2048, 256, 0, stream>>>(x, WQB, rpb, YTATT);     // ATT overwrites dead YT
  k_comb<<<4096, 256, 0, stream>>>(YTATT, LOCB);
  k_dw<<<4096, 256, 0, stream>>>(LOCB, wdw, YTATT);         // DWO overwrites dead ATT
  k_pw<<<8192, 256, 0, stream>>>(YTATT, WPW, BIASPW, OUT);
}

// Round 3
// 1569.667 us; speedup vs baseline: 2.2829x; 1.1665x over previous
//
#include <hip/hip_runtime.h>

typedef unsigned short u16;
typedef __bf16 bf8 __attribute__((ext_vector_type(8)));
typedef float f32x4 __attribute__((ext_vector_type(4)));

// ---------- bf16 helpers for INTERMEDIATE storage (inputs/outputs are fp32) ----------
__device__ __forceinline__ float b2f(u16 u){
  union { unsigned int i; float f; } z; z.i = ((unsigned int)u) << 16; return z.f;
}
__device__ __forceinline__ u16 f2b(float f){
  union { float f; unsigned int i; } z; z.f = f;
  unsigned int lsb = (z.i >> 16) & 1u;
  return (u16)((z.i + 0x7fffu + lsb) >> 16);
}

#define EPSf 1e-5f

// ---------------------------------------------------------------------------
// K0a: fold BN1/BN2 into 3x3 weights (1x1 into center tap) -> W3B bf16 in
// MFMA A-frag layout [ct4][c8 8][tap9][q4][oc64][j8], + BIASL fp32.
// grid 2304 x 256
// ---------------------------------------------------------------------------
__global__ __launch_bounds__(256) void k_prep_w3(
    const float* __restrict__ w1, const float* __restrict__ w2,
    const float* __restrict__ g1, const float* __restrict__ b1,
    const float* __restrict__ m1, const float* __restrict__ v1,
    const float* __restrict__ g2, const float* __restrict__ b2,
    const float* __restrict__ m2, const float* __restrict__ v2,
    u16* __restrict__ W3B, float* __restrict__ BIASL){
  int e = blockIdx.x*256 + threadIdx.x;       // < 589824
  int c = e / 2304; int r = e - c*2304; int s = r / 9; int tap = r - s*9;
  float inv1 = g1[c] * rsqrtf(v1[c] + EPSf);
  float val = w1[e] * inv1;
  if (tap == 4){
    float inv2 = g2[c] * rsqrtf(v2[c] + EPSf);
    val += w2[c*256 + s] * inv2;
  }
  int ct = c >> 6, oc_l = c & 63;
  int c8 = s >> 5, q = (s >> 3) & 3, j = s & 7;
  W3B[((((ct*8 + c8)*9 + tap)*4 + q)*64 + oc_l)*8 + j] = f2b(val);
  if (e < 256){
    float i1 = g1[e] * rsqrtf(v1[e] + EPSf);
    float i2 = g2[e] * rsqrtf(v2[e] + EPSf);
    BIASL[e] = (b1[e] - m1[e]*i1) + (b2[e] - m2[e]*i2);
  }
}

// ---------------------------------------------------------------------------
// K0b: fold BNp into pointwise weights -> WPB bf16 hi/lo split in MFMA A-frag
// layout [half2][ot4][c8 8][q4][oc64][j8] (half stride 65536 u16), + BIASPW.
// ---------------------------------------------------------------------------
__global__ __launch_bounds__(256) void k_prep_pw(
    const float* __restrict__ wpw,
    const float* __restrict__ gp, const float* __restrict__ bp,
    const float* __restrict__ mp, const float* __restrict__ vp,
    u16* __restrict__ WPB, float* __restrict__ BIASPW){
  __shared__ float invp[256], betap[256];
  int t = threadIdx.x;
  float iv = gp[t] * rsqrtf(vp[t] + EPSf);
  invp[t] = iv; betap[t] = bp[t] - mp[t]*iv;
  __syncthreads();
  float bias = 0.f;
  for (int c = 0; c < 256; ++c){
    float w = wpw[t*256 + c];
    float wf = w * invp[c];
    u16 hi = f2b(wf);
    u16 lo = f2b(wf - b2f(hi));
    int idx = ((((t>>6)*8 + (c>>5))*4 + ((c>>3)&3))*64 + (t&63))*8 + (c&7);
    WPB[idx] = hi;
    WPB[65536 + idx] = lo;
    bias += w * betap[c];
  }
  BIASPW[t] = bias;
}

// ---------------------------------------------------------------------------
// K0d: convert wqkv fp32 [768][256] -> bf16 same layout (= [mat3][hd16][outd16][cin256]).
// Directly the MFMA B-fragment feed: lane reads 8 contiguous cin for outd=lane&15.
// grid 768 x 256
// ---------------------------------------------------------------------------
__global__ __launch_bounds__(256) void k_prep_wqkv(
    const float* __restrict__ wqkv, u16* __restrict__ WQB){
  int i = blockIdx.x*256 + threadIdx.x;      // < 196608
  WQB[i] = f2b(wqkv[i]);
}

// ---------------------------------------------------------------------------
// K0c: transpose y (fp32 NCHW) -> YT bf16 NHWC [b][h][w][cin].
// one block per (b,h). grid 512 x 256.
// ---------------------------------------------------------------------------
__global__ __launch_bounds__(256) void k_prep_yT(
    const float* __restrict__ y, u16* __restrict__ YT){
  __shared__ u16 ls[32*264];            // [cin32][w 256(+8)]
  int bh = blockIdx.x; int b = bh >> 8; int h = bh & 255;
  int t = threadIdx.x;
  for (int c8 = 0; c8 < 8; ++c8){
    if (c8) __syncthreads();
    for (int ci = 0; ci < 32; ++ci)
      ls[ci*264 + t] = f2b(y[(b*256 + c8*32 + ci)*65536 + h*256 + t]);
    __syncthreads();
    int tq = t & 3, wl = t >> 2;
    for (int wb = 0; wb < 4; ++wb){
      int w = wb*64 + wl;
      u16 tmp[8];
      #pragma unroll
      for (int j = 0; j < 8; ++j) tmp[j] = ls[(tq*8 + j)*264 + w];
      *(uint4*)(YT + ((b*256 + h)*256 + w)*256 + c8*32 + tq*8) = *(const uint4*)tmp;
    }
  }
}

// ---------------------------------------------------------------------------
// K1: local conv3x3 as implicit GEMM via MFMA 16x16x32 bf16.
// block = 64 oc x 64 px (one output row segment), 4 waves, grid 8192 x 256.
// K loop: 8 cin-chunks x 9 taps. LDS: wt 36864B + yt 16320B = 53184B.
// ---------------------------------------------------------------------------
__global__ __launch_bounds__(256) void k_local(
    const u16* __restrict__ YT, const u16* __restrict__ W3B,
    const float* __restrict__ BIASL, u16* __restrict__ LOCB){
  __shared__ __align__(16) u16 wt[18432];   // [tap9][q4][oc64][j8]
  __shared__ __align__(16) u16 yt[8160];    // [row3][col68 (stride 40)][cin32]
  int bi = blockIdx.x;
  int ct = bi & 3, wsg = (bi>>2)&3, h = (bi>>4)&255, b = bi>>12;
  int w0 = wsg << 6;
  int t = threadIdx.x;
  int wv = t >> 6, lane = t & 63, pxl = lane & 15, quad = lane >> 4;
  f32x4 acc0 = {0.f,0.f,0.f,0.f}, acc1 = acc0, acc2 = acc0, acc3 = acc0;
  const u16* wsrc = W3B + ct*8*18432;
  for (int c8 = 0; c8 < 8; ++c8){
    if (c8) __syncthreads();
    // stage W3B chunk: contiguous 36864 B
    const uint4* gs = (const uint4*)(wsrc + c8*18432);
    uint4* wd = (uint4*)wt;
    #pragma unroll
    for (int i = 0; i < 9; ++i) wd[i*256 + t] = gs[i*256 + t];
    // stage y tile: 3 rows x 66 cols x 32 cin (zero pad OOB)
    for (int e = t; e < 792; e += 256){
      int rc = e >> 2, q = e & 3;
      int row = rc / 66, col = rc - row*66;
      int gh = h - 1 + row, gw = w0 - 1 + col;
      uint4 v = make_uint4(0u,0u,0u,0u);
      if (((unsigned)gh < 256u) && ((unsigned)gw < 256u))
        v = *(const uint4*)(YT + ((b*256 + gh)*256 + gw)*256 + c8*32 + q*8);
      *(uint4*)(yt + (row*68 + col)*40 + q*8) = v;
    }
    __syncthreads();
    #pragma unroll
    for (int tap = 0; tap < 9; ++tap){
      int dr = tap / 3, dc = tap - dr*3;
      bf8 a = *(const bf8*)(wt + ((tap*4 + quad)*64 + wv*16 + pxl)*8);
      int boff = (dr*68 + dc + pxl)*40 + quad*8;
      acc0 = __builtin_amdgcn_mfma_f32_16x16x32_bf16(a, *(const bf8*)(yt + boff       ), acc0, 0,0,0);
      acc1 = __builtin_amdgcn_mfma_f32_16x16x32_bf16(a, *(const bf8*)(yt + boff +  640), acc1, 0,0,0);
      acc2 = __builtin_amdgcn_mfma_f32_16x16x32_bf16(a, *(const bf8*)(yt + boff + 1280), acc2, 0,0,0);
      acc3 = __builtin_amdgcn_mfma_f32_16x16x32_bf16(a, *(const bf8*)(yt + boff + 1920), acc3, 0,0,0);
    }
  }
  int ocb = ct*64 + wv*16 + quad*4;
  float bs[4];
  #pragma unroll
  for (int r = 0; r < 4; ++r) bs[r] = BIASL[ocb + r];
  u16* ob = LOCB + (b*256 + ocb)*65536 + h*256 + w0 + pxl;
  #pragma unroll
  for (int r = 0; r < 4; ++r){
    ob[r*65536 +  0] = f2b(acc0[r] + bs[r]);
    ob[r*65536 + 16] = f2b(acc1[r] + bs[r]);
    ob[r*65536 + 32] = f2b(acc2[r] + bs[r]);
    ob[r*65536 + 48] = f2b(acc3[r] + bs[r]);
  }
}

// ---------------------------------------------------------------------------
// K2: fully-MFMA window attention, software-pipelined: 1 barrier per head.
// Per block: one 8x8 window, 4 waves. Iteration hd: project qkv for head hd+1
// (double-buffered sets), then QK^T MFMA + exp (no max-subtract: |scores|<~6)
// + PV MFMA + rowsum-via-MFMA(ones) for head hd. pb/qb are wave-private
// (lgkmcnt only); kb/vbt cross-wave (the one barrier). LDS 34304 -> 4 blk/CU.
// ---------------------------------------------------------------------------
__global__ __launch_bounds__(256, 4) void k_attn(
    const float* __restrict__ x, const u16* __restrict__ WQB,
    const float* __restrict__ rpb, u16* __restrict__ ATT){
  __shared__ __align__(16) unsigned char smem[34304];
  // xt u16[64][264] @0 (33792B), dead after A-frag hoist. Then union:
  //   set s @ s*12544: qb u16[64][40], kb u16[64][40] @+5120, vbt u16[16][72] @+10240
  //   pb u16[64][72] @25088
  u16* xt = (u16*)smem;
  int t = threadIdx.x;
  int bi = blockIdx.x;
  int b = bi >> 10; int wi = bi & 1023;
  int h0 = (wi >> 5) << 3; int w0 = (wi & 31) << 3;
  int wv = t >> 6, lane = t & 63, pxl = lane & 15, quad = lane >> 4;

  // ---- stage x -> xt bf16 [tok][cin] stride 264
  for (int e = t; e < 16384; e += 256){
    int c = e >> 6; int tk = e & 63;
    int r = tk >> 3, cc = tk & 7;
    xt[tk*264 + c] = f2b(x[((b*256 + c)*256 + (h0+r))*256 + (w0+cc)]);
  }
  __syncthreads();
  // ---- hoist A-frags: af[kc] = X[tok = wv*16+pxl][cin = kc*32+quad*8 ..+7]
  bf8 af[8];
  #pragma unroll
  for (int kc = 0; kc < 8; ++kc)
    af[kc] = *(const bf8*)(xt + (wv*16 + pxl)*264 + kc*32 + quad*8);
  // ---- precompute rpb offsets (x16 prescaled), packed 2/reg
  unsigned int bp[8];
  {
    int row0 = wv*16 + quad*4;
    #pragma unroll
    for (int nt = 0; nt < 4; ++nt){
      int j = nt*16 + pxl; int rj = j >> 3, cj = j & 7;
      int row = row0;     int i0 = (((row>>3) - rj + 7)*15 + ((row&7) - cj + 7))<<4;
      row = row0 + 1;     int i1 = (((row>>3) - rj + 7)*15 + ((row&7) - cj + 7))<<4;
      row = row0 + 2;     int i2 = (((row>>3) - rj + 7)*15 + ((row&7) - cj + 7))<<4;
      row = row0 + 3;     int i3 = (((row>>3) - rj + 7)*15 + ((row&7) - cj + 7))<<4;
      bp[nt*2]   = (unsigned)i0 | ((unsigned)i1 << 16);
      bp[nt*2+1] = (unsigned)i2 | ((unsigned)i3 << 16);
    }
  }
  __syncthreads();                      // xt now dead
  // ---- zero filler cols d=16..31 of qb,kb (both sets) for K=32 zero-pad
  for (int e = t; e < 2048; e += 256){
    int cp = e & 7; int row = (e>>3) & 63; int s2 = (e>>9) & 1; int qk = e >> 10;
    *(unsigned int*)(smem + s2*12544 + qk*5120 + row*80 + 32 + cp*4) = 0u;
  }

  int tok0 = wv*16 + quad*4;
  bf8 one8;
  #pragma unroll
  for (int j = 0; j < 8; ++j) one8[j] = (__bf16)1.0f;

  // qkv projection for head H into set S (MFMA, A from regs, B from L2)
  auto phase_a = [&](int H, int S){
    u16* qb  = (u16*)(smem + S*12544);
    u16* kb  = (u16*)(smem + S*12544 + 5120);
    u16* vbt = (u16*)(smem + S*12544 + 10240);
    #pragma unroll
    for (int mat = 0; mat < 3; ++mat){
      const u16* bbase = WQB + (((mat<<8) + (H<<4) + pxl)<<8) + (quad<<3);
      f32x4 acc = {0.f,0.f,0.f,0.f};
      #pragma unroll
      for (int kc = 0; kc < 8; ++kc){
        bf8 bf = *(const bf8*)(bbase + kc*32);
        acc = __builtin_amdgcn_mfma_f32_16x16x32_bf16(af[kc], bf, acc, 0,0,0);
      }
      if (mat == 0){
        #pragma unroll
        for (int r = 0; r < 4; ++r) qb[(tok0 + r)*40 + pxl] = f2b(acc[r]*0.25f);
      } else if (mat == 1){
        #pragma unroll
        for (int r = 0; r < 4; ++r) kb[(tok0 + r)*40 + pxl] = f2b(acc[r]);
      } else {
        u16 tmp[4];
        #pragma unroll
        for (int r = 0; r < 4; ++r) tmp[r] = f2b(acc[r]);
        *(ushort4*)(vbt + pxl*72 + tok0) = *(const ushort4*)tmp;  // [d][tok]
      }
    }
  };

  phase_a(0, 0);
  __syncthreads();

  for (int hd = 0; hd < 16; ++hd){
    // ---- prefetch rpb bias for this head (L1/L2-resident)
    float bias[16];
    #pragma unroll
    for (int nt = 0; nt < 4; ++nt){
      bias[nt*4+0] = rpb[(bp[nt*2]   & 0xffffu) + hd];
      bias[nt*4+1] = rpb[(bp[nt*2]   >> 16)     + hd];
      bias[nt*4+2] = rpb[(bp[nt*2+1] & 0xffffu) + hd];
      bias[nt*4+3] = rpb[(bp[nt*2+1] >> 16)     + hd];
    }
    // ---- project next head while this head's attention runs
    if (hd < 15) phase_a(hd+1, (hd+1)&1);

    int sb = (hd & 1)*12544;
    u16* qb  = (u16*)(smem + sb);
    u16* kb  = (u16*)(smem + sb + 5120);
    u16* vbt = (u16*)(smem + sb + 10240);
    u16* pb  = (u16*)(smem + 25088);

    // ---- QK^T MFMA + bias + exp (no max-subtract; scores bounded) -> pb bf16
    {
      bf8 aq = *(const bf8*)(qb + (wv*16 + pxl)*40 + quad*8);
      f32x4 sc[4];
      #pragma unroll
      for (int nt = 0; nt < 4; ++nt){
        bf8 bk = *(const bf8*)(kb + (nt*16 + pxl)*40 + quad*8);
        f32x4 z = {0.f,0.f,0.f,0.f};
        sc[nt] = __builtin_amdgcn_mfma_f32_16x16x32_bf16(aq, bk, z, 0,0,0);
      }
      #pragma unroll
      for (int nt = 0; nt < 4; ++nt)
        #pragma unroll
        for (int r = 0; r < 4; ++r){
          float e_ = __expf(sc[nt][r] + bias[nt*4+r]);
          pb[(tok0 + r)*72 + nt*16 + pxl] = f2b(e_);
        }
    }
    // ---- PV MFMA + rowsum via ones-MFMA (pb/vbt reads; pb wave-private)
    {
      const u16* prow = pb + (wv*16 + pxl)*72 + quad*8;
      const u16* vrow = vbt + pxl*72 + quad*8;
      bf8 pa0 = *(const bf8*)(prow);
      bf8 pa1 = *(const bf8*)(prow + 32);
      bf8 vb0 = *(const bf8*)(vrow);
      bf8 vb1 = *(const bf8*)(vrow + 32);
      f32x4 o  = {0.f,0.f,0.f,0.f};
      f32x4 rs = {0.f,0.f,0.f,0.f};
      o  = __builtin_amdgcn_mfma_f32_16x16x32_bf16(pa0, vb0, o, 0,0,0);
      o  = __builtin_amdgcn_mfma_f32_16x16x32_bf16(pa1, vb1, o, 0,0,0);
      rs = __builtin_amdgcn_mfma_f32_16x16x32_bf16(pa0, one8, rs, 0,0,0);
      rs = __builtin_amdgcn_mfma_f32_16x16x32_bf16(pa1, one8, rs, 0,0,0);
      u16 tmp[4];
      #pragma unroll
      for (int r = 0; r < 4; ++r) tmp[r] = f2b(o[r] / rs[r]);
      u16* dst = ATT + (b*256 + (hd<<4) + pxl)*65536
                     + (h0 + wv*2 + (quad>>1))*256 + w0 + (quad&1)*4;
      *(ushort4*)dst = *(const ushort4*)tmp;
    }
    __syncthreads();
  }
}

// ---------------------------------------------------------------------------
// K3: comb = avgpool_v(attn) + avgpool_h(attn) + local, in-place into LOCB.
// ---------------------------------------------------------------------------
__global__ __launch_bounds__(256) void k_comb(
    const u16* __restrict__ ATT, u16* __restrict__ LOCB){
  __shared__ float pt[39][256];
  int bi = blockIdx.x;
  int rb = bi & 7; int c = (bi>>3)&255; int b = bi>>11;
  int h0 = rb<<5;
  int t = threadIdx.x;
  const u16* P = ATT + (b*256 + c)*65536;
  for (int e = t; e < 9984; e += 256){
    int r = e >> 8; int cc = e & 255;
    int g = h0 - 3 + r;
    float v = 0.f;
    if ((unsigned)g < 256u) v = b2f(P[(g<<8) + cc]);
    else if (g == 256) v = b2f(P[(254<<8) + cc]);
    pt[r][cc] = v;
  }
  __syncthreads();
  int w = t;
  float colsum = 0.f;
  #pragma unroll
  for (int k = 0; k < 8; ++k) colsum += pt[k][w];
  u16* O = LOCB + (b*256 + c)*65536 + (h0<<8);
  for (int hr = 0; hr < 32; ++hr){
    const float* prow = pt[hr + 3];
    float s = 0.f;
    #pragma unroll
    for (int j = 0; j < 8; ++j){
      int cc = w - 3 + j;
      float v = 0.f;
      if ((unsigned)cc < 256u) v = prow[cc];
      else if (cc == 256) v = prow[254];
      s += v;
    }
    float res = (colsum + s)*0.125f + b2f(O[(hr<<8) + w]);
    O[(hr<<8) + w] = f2b(res);
    if (hr < 31) colsum += pt[hr+8][w] - pt[hr][w];
  }
}

// ---------------------------------------------------------------------------
// K4: 8x8 depthwise conv, reflect(0,1) pad + zero conv-pad 3 -> DWO (bf16)
// ---------------------------------------------------------------------------
__global__ __launch_bounds__(256) void k_dw(
    const u16* __restrict__ COMB, const float* __restrict__ wdw,
    u16* __restrict__ DWO){
  __shared__ float pt[39][264];
  __shared__ float wl[64];
  int bi = blockIdx.x;
  int rb = bi & 7; int c = (bi>>3)&255; int b = bi>>11;
  int h0 = rb<<5;
  int t = threadIdx.x;
  const u16* P = COMB + (b*256 + c)*65536;
  for (int e = t; e < 10296; e += 256){
    int r = e / 264; int cc = e - r*264;
    int g = h0 - 3 + r;
    int gc = cc - 3;
    int gr  = (g  == 256) ? 254 : g;
    int gcc = (gc == 256) ? 254 : gc;
    float v = 0.f;
    if (((unsigned)gr < 256u) && ((unsigned)gcc < 256u))
      v = b2f(P[(gr<<8) + gcc]);
    pt[r][cc] = v;
  }
  if (t < 64) wl[t] = wdw[(c<<6) + t];
  __syncthreads();
  int w = t;
  for (int hr = 0; hr < 32; ++hr){
    float acc = 0.f;
    #pragma unroll
    for (int i = 0; i < 8; ++i){
      const float* prow = &pt[hr + i][w];
      #pragma unroll
      for (int j = 0; j < 8; ++j)
        acc += wl[(i<<3) + j] * prow[j];
    }
    DWO[(b*256 + c)*65536 + ((h0+hr)<<8) + w] = f2b(acc);
  }
}

// ---------------------------------------------------------------------------
// K5: pointwise 1x1 as implicit GEMM via MFMA (weights bf16 hi+lo -> ~fp32
// weight precision). block = 64 oc x 64 px, 4 waves; K loop 8 cin-chunks,
// double-buffered 10KB LDS, 1 barrier/chunk. grid 8192 x 256.
// ---------------------------------------------------------------------------
__global__ __launch_bounds__(256) void k_pw(
    const u16* __restrict__ DW, const u16* __restrict__ WPB,
    const float* __restrict__ BIASPW, float* __restrict__ OUT){
  __shared__ __align__(16) u16 dt[2][2560];   // [buf][px64 * 40] (k 32 + pad)
  int bi = blockIdx.x;
  int ot = bi & 3; int ptile = bi >> 2;
  int t = threadIdx.x;
  int wv = t >> 6, lane = t & 63, pxl = lane & 15, quad = lane >> 4;
  int n0 = ptile << 6;
  int b = n0 >> 16; int pix0 = n0 & 65535;
  const u16* Dbase = DW + b*16777216 + pix0;
  int spx = t & 63, skl = t >> 6;             // staging: px lane-contig, 4 k-rows/pass
  f32x4 acc[4];
  #pragma unroll
  for (int nt = 0; nt < 4; ++nt) acc[nt] = (f32x4){0.f,0.f,0.f,0.f};
  // prologue: stage chunk 0 -> buf 0
  #pragma unroll
  for (int p = 0; p < 8; ++p){
    int k = skl*8 + p;
    dt[0][spx*40 + k] = Dbase[k*65536 + spx];
  }
  __syncthreads();
  const u16* wbase = WPB + (((ot*8)*4 + quad)*64 + wv*16 + pxl)*8;
  for (int c8 = 0; c8 < 8; ++c8){
    int buf = c8 & 1;
    if (c8 < 7){
      #pragma unroll
      for (int p = 0; p < 8; ++p){
        int k = skl*8 + p;
        dt[buf^1][spx*40 + k] = Dbase[((c8+1)*32 + k)*65536 + spx];
      }
    }
    bf8 ah = *(const bf8*)(wbase + c8*2048);
    bf8 al = *(const bf8*)(wbase + 65536 + c8*2048);
    #pragma unroll
    for (int nt = 0; nt < 4; ++nt){
      bf8 bk = *(const bf8*)(&dt[buf][(nt*16 + pxl)*40 + quad*8]);
      acc[nt] = __builtin_amdgcn_mfma_f32_16x16x32_bf16(ah, bk, acc[nt], 0,0,0);
      acc[nt] = __builtin_amdgcn_mfma_f32_16x16x32_bf16(al, bk, acc[nt], 0,0,0);
    }
    __syncthreads();
  }
  int oc = ot*64 + wv*16 + quad*4;
  float bs[4];
  #pragma unroll
  for (int r = 0; r < 4; ++r) bs[r] = BIASPW[oc + r];
  #pragma unroll
  for (int nt = 0; nt < 4; ++nt)
    #pragma unroll
    for (int r = 0; r < 4; ++r)
      OUT[(b*256 + oc + r)*65536 + pix0 + nt*16 + pxl] = acc[nt][r] + bs[r];
}

// ---------------------------------------------------------------------------
extern "C" void kernel_launch(void* const* d_in, const int* in_sizes, int n_in,
                              void* d_out, int out_size, void* d_ws, size_t ws_size,
                              hipStream_t stream){
  const float* x    = (const float*)d_in[0];
  const float* y    = (const float*)d_in[1];
  const float* wqkv = (const float*)d_in[2];
  const float* wl1  = (const float*)d_in[3];
  const float* g1   = (const float*)d_in[4];
  const float* b1   = (const float*)d_in[5];
  const float* m1   = (const float*)d_in[6];
  const float* v1   = (const float*)d_in[7];
  const float* wl2  = (const float*)d_in[8];
  const float* g2   = (const float*)d_in[9];
  const float* b2   = (const float*)d_in[10];
  const float* m2   = (const float*)d_in[11];
  const float* v2   = (const float*)d_in[12];
  const float* wdw  = (const float*)d_in[13];
  const float* gp   = (const float*)d_in[14];
  const float* bp   = (const float*)d_in[15];
  const float* mp   = (const float*)d_in[16];
  const float* vp   = (const float*)d_in[17];
  const float* wpw  = (const float*)d_in[18];
  const float* rpb  = (const float*)d_in[19];

  float* BIASL  = (float*)d_ws;                    // 256 f32
  u16* WPB      = (u16*)(BIASL + 256);             // 131072 u16 (hi+lo, old WPW slot)
  float* BIASPW = (float*)(WPB + 131072);          // 256 f32
  u16* W3B   = (u16*)(BIASPW + 256);               // 589824 bf16 (MFMA layout)
  u16* WQB   = W3B + 589824;                       // 196608 bf16 qkv weights
  u16* YTATT = WQB + 196608;                       // 33.5M bf16: YT, then ATT, then DWO
  u16* LOCB  = YTATT + 33554432;                   // 33.5M bf16: local -> comb in place
  float* OUT = (float*)d_out;

  k_prep_w3<<<2304, 256, 0, stream>>>(wl1, wl2, g1, b1, m1, v1, g2, b2, m2, v2, W3B, BIASL);
  k_prep_pw<<<1, 256, 0, stream>>>(wpw, gp, bp, mp, vp, WPB, BIASPW);
  k_prep_wqkv<<<768, 256, 0, stream>>>(wqkv, WQB);
  k_prep_yT<<<512, 256, 0, stream>>>(y, YTATT);
  k_local<<<8192, 256, 0, stream>>>(YTATT, W3B, BIASL, LOCB);
  k_attn<<<2048, 256, 0, stream>>>(x, WQB, rpb, YTATT);     // ATT overwrites dead YT
  k_comb<<<4096, 256, 0, stream>>>(YTATT, LOCB);
  k_dw<<<4096, 256, 0, stream>>>(LOCB, wdw, YTATT);         // DWO overwrites dead ATT
  k_pw<<<8192, 256, 0, stream>>>(YTATT, WPB, BIASPW, OUT);
}

// Round 4
// 1465.495 us; speedup vs baseline: 2.4452x; 1.0711x over previous
//
#include <hip/hip_runtime.h>

typedef unsigned short u16;
typedef __bf16 bf8 __attribute__((ext_vector_type(8)));
typedef float f32x4 __attribute__((ext_vector_type(4)));

// ---------- bf16 helpers for INTERMEDIATE storage (inputs/outputs are fp32) ----------
__device__ __forceinline__ float b2f(u16 u){
  union { unsigned int i; float f; } z; z.i = ((unsigned int)u) << 16; return z.f;
}
__device__ __forceinline__ u16 f2b(float f){
  union { float f; unsigned int i; } z; z.f = f;
  unsigned int lsb = (z.i >> 16) & 1u;
  return (u16)((z.i + 0x7fffu + lsb) >> 16);
}

#define EPSf 1e-5f

// ---------------------------------------------------------------------------
// K0a: fold BN1/BN2 into 3x3 weights (1x1 into center tap) -> W3B bf16 in
// MFMA A-frag layout [ct4][c8 8][tap9][q4][oc64][j8], + BIASL fp32.
// ---------------------------------------------------------------------------
__global__ __launch_bounds__(256) void k_prep_w3(
    const float* __restrict__ w1, const float* __restrict__ w2,
    const float* __restrict__ g1, const float* __restrict__ b1,
    const float* __restrict__ m1, const float* __restrict__ v1,
    const float* __restrict__ g2, const float* __restrict__ b2,
    const float* __restrict__ m2, const float* __restrict__ v2,
    u16* __restrict__ W3B, float* __restrict__ BIASL){
  int e = blockIdx.x*256 + threadIdx.x;       // < 589824
  int c = e / 2304; int r = e - c*2304; int s = r / 9; int tap = r - s*9;
  float inv1 = g1[c] * rsqrtf(v1[c] + EPSf);
  float val = w1[e] * inv1;
  if (tap == 4){
    float inv2 = g2[c] * rsqrtf(v2[c] + EPSf);
    val += w2[c*256 + s] * inv2;
  }
  int ct = c >> 6, oc_l = c & 63;
  int c8 = s >> 5, q = (s >> 3) & 3, j = s & 7;
  W3B[((((ct*8 + c8)*9 + tap)*4 + q)*64 + oc_l)*8 + j] = f2b(val);
  if (e < 256){
    float i1 = g1[e] * rsqrtf(v1[e] + EPSf);
    float i2 = g2[e] * rsqrtf(v2[e] + EPSf);
    BIASL[e] = (b1[e] - m1[e]*i1) + (b2[e] - m2[e]*i2);
  }
}

// ---------------------------------------------------------------------------
// K0b: fold BNp into pointwise weights -> WPB bf16 hi/lo split in MFMA A-frag
// layout [half2][ot4][c8 8][q4][oc64][j8] (half stride 65536 u16), + BIASPW.
// ---------------------------------------------------------------------------
__global__ __launch_bounds__(256) void k_prep_pw(
    const float* __restrict__ wpw,
    const float* __restrict__ gp, const float* __restrict__ bp,
    const float* __restrict__ mp, const float* __restrict__ vp,
    u16* __restrict__ WPB, float* __restrict__ BIASPW){
  __shared__ float invp[256], betap[256];
  int t = threadIdx.x;
  float iv = gp[t] * rsqrtf(vp[t] + EPSf);
  invp[t] = iv; betap[t] = bp[t] - mp[t]*iv;
  __syncthreads();
  float bias = 0.f;
  for (int c = 0; c < 256; ++c){
    float w = wpw[t*256 + c];
    float wf = w * invp[c];
    u16 hi = f2b(wf);
    u16 lo = f2b(wf - b2f(hi));
    int idx = ((((t>>6)*8 + (c>>5))*4 + ((c>>3)&3))*64 + (t&63))*8 + (c&7);
    WPB[idx] = hi;
    WPB[65536 + idx] = lo;
    bias += w * betap[c];
  }
  BIASPW[t] = bias;
}

// ---------------------------------------------------------------------------
// K0d: convert wqkv fp32 [768][256] -> bf16 same layout.
// ---------------------------------------------------------------------------
__global__ __launch_bounds__(256) void k_prep_wqkv(
    const float* __restrict__ wqkv, u16* __restrict__ WQB){
  int i = blockIdx.x*256 + threadIdx.x;      // < 196608
  WQB[i] = f2b(wqkv[i]);
}

// ---------------------------------------------------------------------------
// K0c: transpose y (fp32 NCHW) -> YT bf16 NHWC [b][h][w][cin].
// ---------------------------------------------------------------------------
__global__ __launch_bounds__(256) void k_prep_yT(
    const float* __restrict__ y, u16* __restrict__ YT){
  __shared__ u16 ls[32*264];            // [cin32][w 256(+8)]
  int bh = blockIdx.x; int b = bh >> 8; int h = bh & 255;
  int t = threadIdx.x;
  for (int c8 = 0; c8 < 8; ++c8){
    if (c8) __syncthreads();
    for (int ci = 0; ci < 32; ++ci)
      ls[ci*264 + t] = f2b(y[(b*256 + c8*32 + ci)*65536 + h*256 + t]);
    __syncthreads();
    int tq = t & 3, wl = t >> 2;
    for (int wb = 0; wb < 4; ++wb){
      int w = wb*64 + wl;
      u16 tmp[8];
      #pragma unroll
      for (int j = 0; j < 8; ++j) tmp[j] = ls[(tq*8 + j)*264 + w];
      *(uint4*)(YT + ((b*256 + h)*256 + w)*256 + c8*32 + tq*8) = *(const uint4*)tmp;
    }
  }
}

// ---------------------------------------------------------------------------
// K0e: transpose x (fp32 NCHW) -> XT bf16 WINDOW-TILED [b][wi][tok][cin].
// wi = (h/8)*32 + w/8, tok = (h%8)*8 + w%8. Same coalescing as k_prep_yT.
// ---------------------------------------------------------------------------
__global__ __launch_bounds__(256) void k_prep_xT(
    const float* __restrict__ x, u16* __restrict__ XT){
  __shared__ u16 ls[32*264];
  int bh = blockIdx.x; int b = bh >> 8; int h = bh & 255;
  int t = threadIdx.x;
  int wrow = (h>>3)<<5, tokr = (h&7)<<3;
  for (int c8 = 0; c8 < 8; ++c8){
    if (c8) __syncthreads();
    for (int ci = 0; ci < 32; ++ci)
      ls[ci*264 + t] = f2b(x[(b*256 + c8*32 + ci)*65536 + h*256 + t]);
    __syncthreads();
    int tq = t & 3, wl = t >> 2;
    for (int wb = 0; wb < 4; ++wb){
      int w = wb*64 + wl;
      u16 tmp[8];
      #pragma unroll
      for (int j = 0; j < 8; ++j) tmp[j] = ls[(tq*8 + j)*264 + w];
      int wi = wrow + (w>>3), tok = tokr + (w&7);
      *(uint4*)(XT + ((b*1024 + wi)*64 + tok)*256 + c8*32 + tq*8) = *(const uint4*)tmp;
    }
  }
}

// ---------------------------------------------------------------------------
// K1: local conv3x3 as implicit GEMM via MFMA 16x16x32 bf16.
// ---------------------------------------------------------------------------
__global__ __launch_bounds__(256) void k_local(
    const u16* __restrict__ YT, const u16* __restrict__ W3B,
    const float* __restrict__ BIASL, u16* __restrict__ LOCB){
  __shared__ __align__(16) u16 wt[18432];   // [tap9][q4][oc64][j8]
  __shared__ __align__(16) u16 yt[8160];    // [row3][col68 (stride 40)][cin32]
  int bi = blockIdx.x;
  int ct = bi & 3, wsg = (bi>>2)&3, h = (bi>>4)&255, b = bi>>12;
  int w0 = wsg << 6;
  int t = threadIdx.x;
  int wv = t >> 6, lane = t & 63, pxl = lane & 15, quad = lane >> 4;
  f32x4 acc0 = {0.f,0.f,0.f,0.f}, acc1 = acc0, acc2 = acc0, acc3 = acc0;
  const u16* wsrc = W3B + ct*8*18432;
  for (int c8 = 0; c8 < 8; ++c8){
    if (c8) __syncthreads();
    const uint4* gs = (const uint4*)(wsrc + c8*18432);
    uint4* wd = (uint4*)wt;
    #pragma unroll
    for (int i = 0; i < 9; ++i) wd[i*256 + t] = gs[i*256 + t];
    for (int e = t; e < 792; e += 256){
      int rc = e >> 2, q = e & 3;
      int row = rc / 66, col = rc - row*66;
      int gh = h - 1 + row, gw = w0 - 1 + col;
      uint4 v = make_uint4(0u,0u,0u,0u);
      if (((unsigned)gh < 256u) && ((unsigned)gw < 256u))
        v = *(const uint4*)(YT + ((b*256 + gh)*256 + gw)*256 + c8*32 + q*8);
      *(uint4*)(yt + (row*68 + col)*40 + q*8) = v;
    }
    __syncthreads();
    #pragma unroll
    for (int tap = 0; tap < 9; ++tap){
      int dr = tap / 3, dc = tap - dr*3;
      bf8 a = *(const bf8*)(wt + ((tap*4 + quad)*64 + wv*16 + pxl)*8);
      int boff = (dr*68 + dc + pxl)*40 + quad*8;
      acc0 = __builtin_amdgcn_mfma_f32_16x16x32_bf16(a, *(const bf8*)(yt + boff       ), acc0, 0,0,0);
      acc1 = __builtin_amdgcn_mfma_f32_16x16x32_bf16(a, *(const bf8*)(yt + boff +  640), acc1, 0,0,0);
      acc2 = __builtin_amdgcn_mfma_f32_16x16x32_bf16(a, *(const bf8*)(yt + boff + 1280), acc2, 0,0,0);
      acc3 = __builtin_amdgcn_mfma_f32_16x16x32_bf16(a, *(const bf8*)(yt + boff + 1920), acc3, 0,0,0);
    }
  }
  int ocb = ct*64 + wv*16 + quad*4;
  float bs[4];
  #pragma unroll
  for (int r = 0; r < 4; ++r) bs[r] = BIASL[ocb + r];
  u16* ob = LOCB + (b*256 + ocb)*65536 + h*256 + w0 + pxl;
  #pragma unroll
  for (int r = 0; r < 4; ++r){
    ob[r*65536 +  0] = f2b(acc0[r] + bs[r]);
    ob[r*65536 + 16] = f2b(acc1[r] + bs[r]);
    ob[r*65536 + 32] = f2b(acc2[r] + bs[r]);
    ob[r*65536 + 48] = f2b(acc3[r] + bs[r]);
  }
}

// ---------------------------------------------------------------------------
// K2: fully-MFMA window attention. Reads window-tiled XT (32KB contiguous per
// block), writes ATT window-tiled [b][wi][c][tok] IN PLACE over its own XT
// region. Dual-bank register prefetch of WQB weight frags; 1 barrier/head.
// LDS 34304 -> 4 blk/CU (LDS-limited). launch_bounds(256,3) for VGPR room.
// ---------------------------------------------------------------------------
#define LDW(W, H, MAT) { \
  const u16* bb_ = WQB + ((((MAT)<<8) + ((H)<<4) + pxl)<<8) + (quad<<3); \
  _Pragma("unroll") for (int kc_ = 0; kc_ < 8; ++kc_) W[kc_] = *(const bf8*)(bb_ + kc_*32); }

#define DOMAT(W, ACC) { ACC = (f32x4){0.f,0.f,0.f,0.f}; \
  _Pragma("unroll") for (int kc_ = 0; kc_ < 8; ++kc_) \
    ACC = __builtin_amdgcn_mfma_f32_16x16x32_bf16(af[kc_], W[kc_], ACC, 0,0,0); }

#define STQ(ACC, SET) { u16* qb_ = (u16*)(smem + (SET)*12544); \
  _Pragma("unroll") for (int r_ = 0; r_ < 4; ++r_) qb_[(tok0+r_)*40 + pxl] = f2b(ACC[r_]*0.25f); }

#define STK(ACC, SET) { u16* kb_ = (u16*)(smem + (SET)*12544 + 5120); \
  _Pragma("unroll") for (int r_ = 0; r_ < 4; ++r_) kb_[(tok0+r_)*40 + pxl] = f2b(ACC[r_]); }

#define STV(ACC, SET) { u16* vbt_ = (u16*)(smem + (SET)*12544 + 10240); \
  u16 tmp_[4]; _Pragma("unroll") for (int r_ = 0; r_ < 4; ++r_) tmp_[r_] = f2b(ACC[r_]); \
  *(ushort4*)(vbt_ + pxl*72 + tok0) = *(const ushort4*)tmp_; }

#define ATTEND(HD, BIAS) { \
  int sb_ = ((HD)&1)*12544; \
  u16* qb_ = (u16*)(smem + sb_); \
  u16* kb_ = (u16*)(smem + sb_ + 5120); \
  u16* vbt_ = (u16*)(smem + sb_ + 10240); \
  u16* pb_ = (u16*)(smem + 25088); \
  bf8 aq_ = *(const bf8*)(qb_ + (wv*16 + pxl)*40 + quad*8); \
  f32x4 sc_[4]; \
  _Pragma("unroll") for (int nt_ = 0; nt_ < 4; ++nt_){ \
    bf8 bk_ = *(const bf8*)(kb_ + (nt_*16 + pxl)*40 + quad*8); \
    f32x4 z_ = {0.f,0.f,0.f,0.f}; \
    sc_[nt_] = __builtin_amdgcn_mfma_f32_16x16x32_bf16(aq_, bk_, z_, 0,0,0); } \
  _Pragma("unroll") for (int nt_ = 0; nt_ < 4; ++nt_) \
    _Pragma("unroll") for (int r_ = 0; r_ < 4; ++r_){ \
      float e_ = __expf(sc_[nt_][r_] + BIAS[nt_*4+r_]); \
      pb_[(tok0 + r_)*72 + nt_*16 + pxl] = f2b(e_); } \
  const u16* prow_ = pb_ + (wv*16 + pxl)*72 + quad*8; \
  const u16* vrow_ = vbt_ + pxl*72 + quad*8; \
  bf8 pa0_ = *(const bf8*)(prow_); \
  bf8 pa1_ = *(const bf8*)(prow_ + 32); \
  bf8 vb0_ = *(const bf8*)(vrow_); \
  bf8 vb1_ = *(const bf8*)(vrow_ + 32); \
  f32x4 o_ = {0.f,0.f,0.f,0.f}; f32x4 rs_ = {0.f,0.f,0.f,0.f}; \
  o_ = __builtin_amdgcn_mfma_f32_16x16x32_bf16(pa0_, vb0_, o_, 0,0,0); \
  o_ = __builtin_amdgcn_mfma_f32_16x16x32_bf16(pa1_, vb1_, o_, 0,0,0); \
  rs_ = __builtin_amdgcn_mfma_f32_16x16x32_bf16(pa0_, one8, rs_, 0,0,0); \
  rs_ = __builtin_amdgcn_mfma_f32_16x16x32_bf16(pa1_, one8, rs_, 0,0,0); \
  u16 tmp_[4]; \
  _Pragma("unroll") for (int r_ = 0; r_ < 4; ++r_) tmp_[r_] = f2b(o_[r_] / rs_[r_]); \
  u16* dst_ = ATT + ((b*1024 + wi)<<14) + (((HD)<<4) + pxl)*64 \
                  + wv*16 + ((quad>>1)<<3) + ((quad&1)<<2); \
  *(ushort4*)dst_ = *(const ushort4*)tmp_; }

#define BODY(HD, X, Y) { \
  float bias_[16]; \
  _Pragma("unroll") for (int n2_ = 0; n2_ < 4; ++n2_){ \
    bias_[n2_*4+0] = rpb[(bp[n2_*2]   & 0xffffu) + (HD)]; \
    bias_[n2_*4+1] = rpb[(bp[n2_*2]   >> 16)     + (HD)]; \
    bias_[n2_*4+2] = rpb[(bp[n2_*2+1] & 0xffffu) + (HD)]; \
    bias_[n2_*4+3] = rpb[(bp[n2_*2+1] >> 16)     + (HD)]; } \
  if ((HD) < 15){ \
    int ns_ = ((HD)+1)&1; \
    LDW(Y, (HD)+1, 1); \
    f32x4 acq_; DOMAT(X, acq_); STQ(acq_, ns_); \
    LDW(X, (HD)+1, 2); \
    f32x4 ack_; DOMAT(Y, ack_); STK(ack_, ns_); \
    int h2_ = ((HD)+2 > 15) ? 15 : (HD)+2; \
    LDW(Y, h2_, 0); \
    f32x4 acv_; DOMAT(X, acv_); STV(acv_, ns_); } \
  ATTEND(HD, bias_); \
  __syncthreads(); }

__global__ __launch_bounds__(256, 3) void k_attn(
    const u16* __restrict__ XT, const u16* __restrict__ WQB,
    const float* __restrict__ rpb, u16* __restrict__ ATT){
  __shared__ __align__(16) unsigned char smem[34304];
  // xt u16[64][264] @0 (33792B), dead after A-frag hoist. Then union:
  //   set s @ s*12544: qb u16[64][40], kb u16[64][40] @+5120, vbt u16[16][72] @+10240
  //   pb u16[64][72] @25088
  u16* xt = (u16*)smem;
  int t = threadIdx.x;
  int bi = blockIdx.x;
  int b = bi >> 10; int wi = bi & 1023;
  int wv = t >> 6, lane = t & 63, pxl = lane & 15, quad = lane >> 4;
  int tok0 = wv*16 + quad*4;

  bf8 wA[8], wB[8];
  LDW(wA, 0, 0);                       // issue early: hides under staging

  // ---- stage XT window block: 32KB fully contiguous
  const u16* src = XT + ((b*1024 + wi)<<14);
  for (int e = t; e < 2048; e += 256)
    *(uint4*)(xt + (e>>5)*264 + (e&31)*8) = *(const uint4*)(src + e*8);
  __syncthreads();
  // ---- hoist A-frags
  bf8 af[8];
  #pragma unroll
  for (int kc = 0; kc < 8; ++kc)
    af[kc] = *(const bf8*)(xt + (wv*16 + pxl)*264 + kc*32 + quad*8);
  // ---- precompute rpb offsets (x16 prescaled), packed 2/reg
  unsigned int bp[8];
  {
    int row0 = tok0;
    #pragma unroll
    for (int nt = 0; nt < 4; ++nt){
      int j = nt*16 + pxl; int rj = j >> 3, cj = j & 7;
      int row = row0;     int i0 = (((row>>3) - rj + 7)*15 + ((row&7) - cj + 7))<<4;
      row = row0 + 1;     int i1 = (((row>>3) - rj + 7)*15 + ((row&7) - cj + 7))<<4;
      row = row0 + 2;     int i2 = (((row>>3) - rj + 7)*15 + ((row&7) - cj + 7))<<4;
      row = row0 + 3;     int i3 = (((row>>3) - rj + 7)*15 + ((row&7) - cj + 7))<<4;
      bp[nt*2]   = (unsigned)i0 | ((unsigned)i1 << 16);
      bp[nt*2+1] = (unsigned)i2 | ((unsigned)i3 << 16);
    }
  }
  __syncthreads();                      // xt now dead
  // ---- zero filler cols d=16..31 of qb,kb (both sets) for K=32 zero-pad
  for (int e = t; e < 2048; e += 256){
    int cp = e & 7; int row = (e>>3) & 63; int s2 = (e>>9) & 1; int qk = e >> 10;
    *(unsigned int*)(smem + s2*12544 + qk*5120 + row*80 + 32 + cp*4) = 0u;
  }
  bf8 one8;
  #pragma unroll
  for (int j = 0; j < 8; ++j) one8[j] = (__bf16)1.0f;

  // ---- prologue: project head 0 into set 0; ends with q-weights(1) in wB
  {
    LDW(wB, 0, 1);
    f32x4 a0; DOMAT(wA, a0); STQ(a0, 0);
    LDW(wA, 0, 2);
    f32x4 a1; DOMAT(wB, a1); STK(a1, 0);
    LDW(wB, 1, 0);
    f32x4 a2; DOMAT(wA, a2); STV(a2, 0);
  }
  __syncthreads();

  for (int hp = 0; hp < 8; ++hp){
    int hd0 = hp*2;
    BODY(hd0,   wB, wA);
    BODY(hd0+1, wA, wB);
  }
}

// ---------------------------------------------------------------------------
// K3: comb = avgpool_v(attn) + avgpool_h(attn) + local, in-place into LOCB.
// ATT is window-tiled [b][wi][c][tok]; stage uint4 per window-row (16B).
// ---------------------------------------------------------------------------
__global__ __launch_bounds__(256) void k_comb(
    const u16* __restrict__ ATT, u16* __restrict__ LOCB){
  __shared__ float pt[39][256];
  int bi = blockIdx.x;
  int rb = bi & 7; int c = (bi>>3)&255; int b = bi>>11;
  int h0 = rb<<5;
  int t = threadIdx.x;
  const u16* Pb = ATT + (b*1024<<14) + c*64;
  for (int e = t; e < 1248; e += 256){
    int r = e >> 5; int w8 = e & 31;
    int g = h0 - 3 + r;
    int gg = (g == 256) ? 254 : g;
    if ((unsigned)gg < 256u){
      const u16* src = Pb + (((gg>>3)*32 + w8)<<14) + ((gg&7)<<3);
      uint4 q4 = *(const uint4*)src;
      pt[r][w8*8+0] = b2f((u16)(q4.x & 0xffffu));
      pt[r][w8*8+1] = b2f((u16)(q4.x >> 16));
      pt[r][w8*8+2] = b2f((u16)(q4.y & 0xffffu));
      pt[r][w8*8+3] = b2f((u16)(q4.y >> 16));
      pt[r][w8*8+4] = b2f((u16)(q4.z & 0xffffu));
      pt[r][w8*8+5] = b2f((u16)(q4.z >> 16));
      pt[r][w8*8+6] = b2f((u16)(q4.w & 0xffffu));
      pt[r][w8*8+7] = b2f((u16)(q4.w >> 16));
    } else {
      #pragma unroll
      for (int j = 0; j < 8; ++j) pt[r][w8*8+j] = 0.f;
    }
  }
  __syncthreads();
  int w = t;
  float colsum = 0.f;
  #pragma unroll
  for (int k = 0; k < 8; ++k) colsum += pt[k][w];
  u16* O = LOCB + (b*256 + c)*65536 + (h0<<8);
  for (int hr = 0; hr < 32; ++hr){
    const float* prow = pt[hr + 3];
    float s = 0.f;
    #pragma unroll
    for (int j = 0; j < 8; ++j){
      int cc = w - 3 + j;
      float v = 0.f;
      if ((unsigned)cc < 256u) v = prow[cc];
      else if (cc == 256) v = prow[254];
      s += v;
    }
    float res = (colsum + s)*0.125f + b2f(O[(hr<<8) + w]);
    O[(hr<<8) + w] = f2b(res);
    if (hr < 31) colsum += pt[hr+8][w] - pt[hr][w];
  }
}

// ---------------------------------------------------------------------------
// K4: 8x8 depthwise conv, reflect(0,1) pad + zero conv-pad 3 -> DWO (bf16)
// ---------------------------------------------------------------------------
__global__ __launch_bounds__(256) void k_dw(
    const u16* __restrict__ COMB, const float* __restrict__ wdw,
    u16* __restrict__ DWO){
  __shared__ float pt[39][264];
  __shared__ float wl[64];
  int bi = blockIdx.x;
  int rb = bi & 7; int c = (bi>>3)&255; int b = bi>>11;
  int h0 = rb<<5;
  int t = threadIdx.x;
  const u16* P = COMB + (b*256 + c)*65536;
  for (int e = t; e < 10296; e += 256){
    int r = e / 264; int cc = e - r*264;
    int g = h0 - 3 + r;
    int gc = cc - 3;
    int gr  = (g  == 256) ? 254 : g;
    int gcc = (gc == 256) ? 254 : gc;
    float v = 0.f;
    if (((unsigned)gr < 256u) && ((unsigned)gcc < 256u))
      v = b2f(P[(gr<<8) + gcc]);
    pt[r][cc] = v;
  }
  if (t < 64) wl[t] = wdw[(c<<6) + t];
  __syncthreads();
  int w = t;
  for (int hr = 0; hr < 32; ++hr){
    float acc = 0.f;
    #pragma unroll
    for (int i = 0; i < 8; ++i){
      const float* prow = &pt[hr + i][w];
      #pragma unroll
      for (int j = 0; j < 8; ++j)
        acc += wl[(i<<3) + j] * prow[j];
    }
    DWO[(b*256 + c)*65536 + ((h0+hr)<<8) + w] = f2b(acc);
  }
}

// ---------------------------------------------------------------------------
// K5: pointwise 1x1 as implicit GEMM via MFMA (weights bf16 hi+lo).
// ---------------------------------------------------------------------------
__global__ __launch_bounds__(256) void k_pw(
    const u16* __restrict__ DW, const u16* __restrict__ WPB,
    const float* __restrict__ BIASPW, float* __restrict__ OUT){
  __shared__ __align__(16) u16 dt[2][2560];   // [buf][px64 * 40] (k 32 + pad)
  int bi = blockIdx.x;
  int ot = bi & 3; int ptile = bi >> 2;
  int t = threadIdx.x;
  int wv = t >> 6, lane = t & 63, pxl = lane & 15, quad = lane >> 4;
  int n0 = ptile << 6;
  int b = n0 >> 16; int pix0 = n0 & 65535;
  const u16* Dbase = DW + b*16777216 + pix0;
  int spx = t & 63, skl = t >> 6;
  f32x4 acc[4];
  #pragma unroll
  for (int nt = 0; nt < 4; ++nt) acc[nt] = (f32x4){0.f,0.f,0.f,0.f};
  #pragma unroll
  for (int p = 0; p < 8; ++p){
    int k = skl*8 + p;
    dt[0][spx*40 + k] = Dbase[k*65536 + spx];
  }
  __syncthreads();
  const u16* wbase = WPB + (((ot*8)*4 + quad)*64 + wv*16 + pxl)*8;
  for (int c8 = 0; c8 < 8; ++c8){
    int buf = c8 & 1;
    if (c8 < 7){
      #pragma unroll
      for (int p = 0; p < 8; ++p){
        int k = skl*8 + p;
        dt[buf^1][spx*40 + k] = Dbase[((c8+1)*32 + k)*65536 + spx];
      }
    }
    bf8 ah = *(const bf8*)(wbase + c8*2048);
    bf8 al = *(const bf8*)(wbase + 65536 + c8*2048);
    #pragma unroll
    for (int nt = 0; nt < 4; ++nt){
      bf8 bk = *(const bf8*)(&dt[buf][(nt*16 + pxl)*40 + quad*8]);
      acc[nt] = __builtin_amdgcn_mfma_f32_16x16x32_bf16(ah, bk, acc[nt], 0,0,0);
      acc[nt] = __builtin_amdgcn_mfma_f32_16x16x32_bf16(al, bk, acc[nt], 0,0,0);
    }
    __syncthreads();
  }
  int oc = ot*64 + wv*16 + quad*4;
  float bs[4];
  #pragma unroll
  for (int r = 0; r < 4; ++r) bs[r] = BIASPW[oc + r];
  #pragma unroll
  for (int nt = 0; nt < 4; ++nt)
    #pragma unroll
    for (int r = 0; r < 4; ++r)
      OUT[(b*256 + oc + r)*65536 + pix0 + nt*16 + pxl] = acc[nt][r] + bs[r];
}

// ---------------------------------------------------------------------------
extern "C" void kernel_launch(void* const* d_in, const int* in_sizes, int n_in,
                              void* d_out, int out_size, void* d_ws, size_t ws_size,
                              hipStream_t stream){
  const float* x    = (const float*)d_in[0];
  const float* y    = (const float*)d_in[1];
  const float* wqkv = (const float*)d_in[2];
  const float* wl1  = (const float*)d_in[3];
  const float* g1   = (const float*)d_in[4];
  const float* b1   = (const float*)d_in[5];
  const float* m1   = (const float*)d_in[6];
  const float* v1   = (const float*)d_in[7];
  const float* wl2  = (const float*)d_in[8];
  const float* g2   = (const float*)d_in[9];
  const float* b2   = (const float*)d_in[10];
  const float* m2   = (const float*)d_in[11];
  const float* v2   = (const float*)d_in[12];
  const float* wdw  = (const float*)d_in[13];
  const float* gp   = (const float*)d_in[14];
  const float* bp   = (const float*)d_in[15];
  const float* mp   = (const float*)d_in[16];
  const float* vp   = (const float*)d_in[17];
  const float* wpw  = (const float*)d_in[18];
  const float* rpb  = (const float*)d_in[19];

  float* BIASL  = (float*)d_ws;                    // 256 f32
  u16* WPB      = (u16*)(BIASL + 256);             // 131072 u16 (hi+lo)
  float* BIASPW = (float*)(WPB + 131072);          // 256 f32
  u16* W3B   = (u16*)(BIASPW + 256);               // 589824 bf16 (MFMA layout)
  u16* WQB   = W3B + 589824;                       // 196608 bf16 qkv weights
  u16* R1    = WQB + 196608;                       // 33.5M bf16: YT -> XT -> ATT -> DWO
  u16* R2    = R1 + 33554432;                      // 33.5M bf16: local -> comb in place
  float* OUT = (float*)d_out;

  k_prep_w3<<<2304, 256, 0, stream>>>(wl1, wl2, g1, b1, m1, v1, g2, b2, m2, v2, W3B, BIASL);
  k_prep_pw<<<1, 256, 0, stream>>>(wpw, gp, bp, mp, vp, WPB, BIASPW);
  k_prep_wqkv<<<768, 256, 0, stream>>>(wqkv, WQB);
  k_prep_yT<<<512, 256, 0, stream>>>(y, R1);
  k_local<<<8192, 256, 0, stream>>>(R1, W3B, BIASL, R2);
  k_prep_xT<<<512, 256, 0, stream>>>(x, R1);                // overwrites dead YT
  k_attn<<<2048, 256, 0, stream>>>(R1, WQB, rpb, R1);       // ATT over XT in place
  k_comb<<<4096, 256, 0, stream>>>(R1, R2);
  k_dw<<<4096, 256, 0, stream>>>(R2, wdw, R1);              // DWO over dead ATT
  k_pw<<<8192, 256, 0, stream>>>(R1, WPB, BIASPW, OUT);
}

// Round 5
// 1360.175 us; speedup vs baseline: 2.6345x; 1.0774x over previous
//
#include <hip/hip_runtime.h>

typedef unsigned short u16;
typedef __bf16 bf8 __attribute__((ext_vector_type(8)));
typedef float f32x4 __attribute__((ext_vector_type(4)));

// ---------- bf16 helpers for INTERMEDIATE storage (inputs/outputs are fp32) ----------
__device__ __forceinline__ float b2f(u16 u){
  union { unsigned int i; float f; } z; z.i = ((unsigned int)u) << 16; return z.f;
}
__device__ __forceinline__ u16 f2b(float f){
  union { float f; unsigned int i; } z; z.f = f;
  unsigned int lsb = (z.i >> 16) & 1u;
  return (u16)((z.i + 0x7fffu + lsb) >> 16);
}

#define EPSf 1e-5f

// ---------------------------------------------------------------------------
// K0a: fold BN1/BN2 into 3x3 weights (1x1 into center tap) -> W3B bf16 in
// MFMA A-frag layout [ct4][c8 8][tap9][q4][oc64][j8], + BIASL fp32.
// ---------------------------------------------------------------------------
__global__ __launch_bounds__(256) void k_prep_w3(
    const float* __restrict__ w1, const float* __restrict__ w2,
    const float* __restrict__ g1, const float* __restrict__ b1,
    const float* __restrict__ m1, const float* __restrict__ v1,
    const float* __restrict__ g2, const float* __restrict__ b2,
    const float* __restrict__ m2, const float* __restrict__ v2,
    u16* __restrict__ W3B, float* __restrict__ BIASL){
  int e = blockIdx.x*256 + threadIdx.x;       // < 589824
  int c = e / 2304; int r = e - c*2304; int s = r / 9; int tap = r - s*9;
  float inv1 = g1[c] * rsqrtf(v1[c] + EPSf);
  float val = w1[e] * inv1;
  if (tap == 4){
    float inv2 = g2[c] * rsqrtf(v2[c] + EPSf);
    val += w2[c*256 + s] * inv2;
  }
  int ct = c >> 6, oc_l = c & 63;
  int c8 = s >> 5, q = (s >> 3) & 3, j = s & 7;
  W3B[((((ct*8 + c8)*9 + tap)*4 + q)*64 + oc_l)*8 + j] = f2b(val);
  if (e < 256){
    float i1 = g1[e] * rsqrtf(v1[e] + EPSf);
    float i2 = g2[e] * rsqrtf(v2[e] + EPSf);
    BIASL[e] = (b1[e] - m1[e]*i1) + (b2[e] - m2[e]*i2);
  }
}

// ---------------------------------------------------------------------------
// K0b: fold BNp into pointwise weights -> WPB bf16 hi/lo split in MFMA A-frag
// layout, + BIASPW. Parallel: one block per oc, wave+LDS reduce for bias.
// grid 256 x 256
// ---------------------------------------------------------------------------
__global__ __launch_bounds__(256) void k_prep_pw(
    const float* __restrict__ wpw,
    const float* __restrict__ gp, const float* __restrict__ bp,
    const float* __restrict__ mp, const float* __restrict__ vp,
    u16* __restrict__ WPB, float* __restrict__ BIASPW){
  __shared__ float red[4];
  int oc = blockIdx.x; int c = threadIdx.x;
  float iv = gp[c] * rsqrtf(vp[c] + EPSf);
  float beta = bp[c] - mp[c]*iv;
  float w = wpw[oc*256 + c];
  float wf = w * iv;
  u16 hi = f2b(wf);
  u16 lo = f2b(wf - b2f(hi));
  int idx = ((((oc>>6)*8 + (c>>5))*4 + ((c>>3)&3))*64 + (oc&63))*8 + (c&7);
  WPB[idx] = hi;
  WPB[65536 + idx] = lo;
  float s = w * beta;
  #pragma unroll
  for (int off = 1; off < 64; off <<= 1) s += __shfl_xor(s, off);
  if ((c & 63) == 0) red[c>>6] = s;
  __syncthreads();
  if (c == 0) BIASPW[oc] = red[0] + red[1] + red[2] + red[3];
}

// ---------------------------------------------------------------------------
// K0d: convert wqkv fp32 [768][256] -> bf16 same layout.
// ---------------------------------------------------------------------------
__global__ __launch_bounds__(256) void k_prep_wqkv(
    const float* __restrict__ wqkv, u16* __restrict__ WQB){
  int i = blockIdx.x*256 + threadIdx.x;      // < 196608
  WQB[i] = f2b(wqkv[i]);
}

// ---------------------------------------------------------------------------
// K0f: precompute attention bias table in the EXACT per-thread consumption
// layout: BIAST[((hd*4 + nt)*256 + t)*4 + r]. 256KB, L2-resident, so k_attn
// reads it as 4 fully-coalesced float4 loads per head instead of 16 divergent
// gathers (TA-pipe relief). grid 64 x 256 (blockIdx = hd*4 + nt).
// ---------------------------------------------------------------------------
__global__ __launch_bounds__(256) void k_prep_bias(
    const float* __restrict__ rpb, float* __restrict__ BIAST){
  int hd = blockIdx.x >> 2, nt = blockIdx.x & 3;
  int t = threadIdx.x;
  int wv = t >> 6, lane = t & 63, pxl = lane & 15, quad = lane >> 4;
  int tok0 = wv*16 + quad*4;
  int j = nt*16 + pxl; int rj = j >> 3, cj = j & 7;
  float4 v;
  float* vp_ = (float*)&v;
  #pragma unroll
  for (int r = 0; r < 4; ++r){
    int row = tok0 + r;
    int idx = ((row>>3) - rj + 7)*15 + ((row&7) - cj + 7);
    vp_[r] = rpb[(idx<<4) + hd];
  }
  *(float4*)(BIAST + ((blockIdx.x*256) + t)*4) = v;
}

// ---------------------------------------------------------------------------
// K0c: transpose y (fp32 NCHW) -> YT bf16 NHWC [b][h][w][cin].
// ---------------------------------------------------------------------------
__global__ __launch_bounds__(256) void k_prep_yT(
    const float* __restrict__ y, u16* __restrict__ YT){
  __shared__ u16 ls[32*264];            // [cin32][w 256(+8)]
  int bh = blockIdx.x; int b = bh >> 8; int h = bh & 255;
  int t = threadIdx.x;
  for (int c8 = 0; c8 < 8; ++c8){
    if (c8) __syncthreads();
    for (int ci = 0; ci < 32; ++ci)
      ls[ci*264 + t] = f2b(y[(b*256 + c8*32 + ci)*65536 + h*256 + t]);
    __syncthreads();
    int tq = t & 3, wl = t >> 2;
    for (int wb = 0; wb < 4; ++wb){
      int w = wb*64 + wl;
      u16 tmp[8];
      #pragma unroll
      for (int j = 0; j < 8; ++j) tmp[j] = ls[(tq*8 + j)*264 + w];
      *(uint4*)(YT + ((b*256 + h)*256 + w)*256 + c8*32 + tq*8) = *(const uint4*)tmp;
    }
  }
}

// ---------------------------------------------------------------------------
// K0e: transpose x (fp32 NCHW) -> XT bf16 WINDOW-TILED [b][wi][tok][cin].
// ---------------------------------------------------------------------------
__global__ __launch_bounds__(256) void k_prep_xT(
    const float* __restrict__ x, u16* __restrict__ XT){
  __shared__ u16 ls[32*264];
  int bh = blockIdx.x; int b = bh >> 8; int h = bh & 255;
  int t = threadIdx.x;
  int wrow = (h>>3)<<5, tokr = (h&7)<<3;
  for (int c8 = 0; c8 < 8; ++c8){
    if (c8) __syncthreads();
    for (int ci = 0; ci < 32; ++ci)
      ls[ci*264 + t] = f2b(x[(b*256 + c8*32 + ci)*65536 + h*256 + t]);
    __syncthreads();
    int tq = t & 3, wl = t >> 2;
    for (int wb = 0; wb < 4; ++wb){
      int w = wb*64 + wl;
      u16 tmp[8];
      #pragma unroll
      for (int j = 0; j < 8; ++j) tmp[j] = ls[(tq*8 + j)*264 + w];
      int wi = wrow + (w>>3), tok = tokr + (w&7);
      *(uint4*)(XT + ((b*1024 + wi)*64 + tok)*256 + c8*32 + tq*8) = *(const uint4*)tmp;
    }
  }
}

// ---------------------------------------------------------------------------
// K1: local conv3x3 as implicit GEMM via MFMA 16x16x32 bf16.
// ---------------------------------------------------------------------------
__global__ __launch_bounds__(256) void k_local(
    const u16* __restrict__ YT, const u16* __restrict__ W3B,
    const float* __restrict__ BIASL, u16* __restrict__ LOCB){
  __shared__ __align__(16) u16 wt[18432];   // [tap9][q4][oc64][j8]
  __shared__ __align__(16) u16 yt[8160];    // [row3][col68 (stride 40)][cin32]
  int bi = blockIdx.x;
  int ct = bi & 3, wsg = (bi>>2)&3, h = (bi>>4)&255, b = bi>>12;
  int w0 = wsg << 6;
  int t = threadIdx.x;
  int wv = t >> 6, lane = t & 63, pxl = lane & 15, quad = lane >> 4;
  f32x4 acc0 = {0.f,0.f,0.f,0.f}, acc1 = acc0, acc2 = acc0, acc3 = acc0;
  const u16* wsrc = W3B + ct*8*18432;
  for (int c8 = 0; c8 < 8; ++c8){
    if (c8) __syncthreads();
    const uint4* gs = (const uint4*)(wsrc + c8*18432);
    uint4* wd = (uint4*)wt;
    #pragma unroll
    for (int i = 0; i < 9; ++i) wd[i*256 + t] = gs[i*256 + t];
    for (int e = t; e < 792; e += 256){
      int rc = e >> 2, q = e & 3;
      int row = rc / 66, col = rc - row*66;
      int gh = h - 1 + row, gw = w0 - 1 + col;
      uint4 v = make_uint4(0u,0u,0u,0u);
      if (((unsigned)gh < 256u) && ((unsigned)gw < 256u))
        v = *(const uint4*)(YT + ((b*256 + gh)*256 + gw)*256 + c8*32 + q*8);
      *(uint4*)(yt + (row*68 + col)*40 + q*8) = v;
    }
    __syncthreads();
    #pragma unroll
    for (int tap = 0; tap < 9; ++tap){
      int dr = tap / 3, dc = tap - dr*3;
      bf8 a = *(const bf8*)(wt + ((tap*4 + quad)*64 + wv*16 + pxl)*8);
      int boff = (dr*68 + dc + pxl)*40 + quad*8;
      acc0 = __builtin_amdgcn_mfma_f32_16x16x32_bf16(a, *(const bf8*)(yt + boff       ), acc0, 0,0,0);
      acc1 = __builtin_amdgcn_mfma_f32_16x16x32_bf16(a, *(const bf8*)(yt + boff +  640), acc1, 0,0,0);
      acc2 = __builtin_amdgcn_mfma_f32_16x16x32_bf16(a, *(const bf8*)(yt + boff + 1280), acc2, 0,0,0);
      acc3 = __builtin_amdgcn_mfma_f32_16x16x32_bf16(a, *(const bf8*)(yt + boff + 1920), acc3, 0,0,0);
    }
  }
  int ocb = ct*64 + wv*16 + quad*4;
  float bs[4];
  #pragma unroll
  for (int r = 0; r < 4; ++r) bs[r] = BIASL[ocb + r];
  u16* ob = LOCB + (b*256 + ocb)*65536 + h*256 + w0 + pxl;
  #pragma unroll
  for (int r = 0; r < 4; ++r){
    ob[r*65536 +  0] = f2b(acc0[r] + bs[r]);
    ob[r*65536 + 16] = f2b(acc1[r] + bs[r]);
    ob[r*65536 + 32] = f2b(acc2[r] + bs[r]);
    ob[r*65536 + 48] = f2b(acc3[r] + bs[r]);
  }
}

// ---------------------------------------------------------------------------
// K2: fully-MFMA window attention. Reads window-tiled XT (32KB contiguous per
// block), writes ATT window-tiled [b][wi][c][tok] IN PLACE over its own XT
// region. Dual-bank register prefetch of WQB weight frags; bias via coalesced
// BIAST loads; 1 barrier/head. LDS 34304. launch_bounds(256,3).
// ---------------------------------------------------------------------------
#define LDW(W, H, MAT) { \
  const u16* bb_ = WQB + ((((MAT)<<8) + ((H)<<4) + pxl)<<8) + (quad<<3); \
  _Pragma("unroll") for (int kc_ = 0; kc_ < 8; ++kc_) W[kc_] = *(const bf8*)(bb_ + kc_*32); }

#define DOMAT(W, ACC) { ACC = (f32x4){0.f,0.f,0.f,0.f}; \
  _Pragma("unroll") for (int kc_ = 0; kc_ < 8; ++kc_) \
    ACC = __builtin_amdgcn_mfma_f32_16x16x32_bf16(af[kc_], W[kc_], ACC, 0,0,0); }

#define STQ(ACC, SET) { u16* qb_ = (u16*)(smem + (SET)*12544); \
  _Pragma("unroll") for (int r_ = 0; r_ < 4; ++r_) qb_[(tok0+r_)*40 + pxl] = f2b(ACC[r_]*0.25f); }

#define STK(ACC, SET) { u16* kb_ = (u16*)(smem + (SET)*12544 + 5120); \
  _Pragma("unroll") for (int r_ = 0; r_ < 4; ++r_) kb_[(tok0+r_)*40 + pxl] = f2b(ACC[r_]); }

#define STV(ACC, SET) { u16* vbt_ = (u16*)(smem + (SET)*12544 + 10240); \
  u16 tmp_[4]; _Pragma("unroll") for (int r_ = 0; r_ < 4; ++r_) tmp_[r_] = f2b(ACC[r_]); \
  *(ushort4*)(vbt_ + pxl*72 + tok0) = *(const ushort4*)tmp_; }

#define ATTEND(HD, BIAS) { \
  int sb_ = ((HD)&1)*12544; \
  u16* qb_ = (u16*)(smem + sb_); \
  u16* kb_ = (u16*)(smem + sb_ + 5120); \
  u16* vbt_ = (u16*)(smem + sb_ + 10240); \
  u16* pb_ = (u16*)(smem + 25088); \
  bf8 aq_ = *(const bf8*)(qb_ + (wv*16 + pxl)*40 + quad*8); \
  f32x4 sc_[4]; \
  _Pragma("unroll") for (int nt_ = 0; nt_ < 4; ++nt_){ \
    bf8 bk_ = *(const bf8*)(kb_ + (nt_*16 + pxl)*40 + quad*8); \
    f32x4 z_ = {0.f,0.f,0.f,0.f}; \
    sc_[nt_] = __builtin_amdgcn_mfma_f32_16x16x32_bf16(aq_, bk_, z_, 0,0,0); } \
  _Pragma("unroll") for (int nt_ = 0; nt_ < 4; ++nt_) \
    _Pragma("unroll") for (int r_ = 0; r_ < 4; ++r_){ \
      float e_ = __expf(sc_[nt_][r_] + BIAS[nt_*4+r_]); \
      pb_[(tok0 + r_)*72 + nt_*16 + pxl] = f2b(e_); } \
  const u16* prow_ = pb_ + (wv*16 + pxl)*72 + quad*8; \
  const u16* vrow_ = vbt_ + pxl*72 + quad*8; \
  bf8 pa0_ = *(const bf8*)(prow_); \
  bf8 pa1_ = *(const bf8*)(prow_ + 32); \
  bf8 vb0_ = *(const bf8*)(vrow_); \
  bf8 vb1_ = *(const bf8*)(vrow_ + 32); \
  f32x4 o_ = {0.f,0.f,0.f,0.f}; f32x4 rs_ = {0.f,0.f,0.f,0.f}; \
  o_ = __builtin_amdgcn_mfma_f32_16x16x32_bf16(pa0_, vb0_, o_, 0,0,0); \
  o_ = __builtin_amdgcn_mfma_f32_16x16x32_bf16(pa1_, vb1_, o_, 0,0,0); \
  rs_ = __builtin_amdgcn_mfma_f32_16x16x32_bf16(pa0_, one8, rs_, 0,0,0); \
  rs_ = __builtin_amdgcn_mfma_f32_16x16x32_bf16(pa1_, one8, rs_, 0,0,0); \
  u16 tmp_[4]; \
  _Pragma("unroll") for (int r_ = 0; r_ < 4; ++r_) tmp_[r_] = f2b(o_[r_] / rs_[r_]); \
  u16* dst_ = ATT + ((b*1024 + wi)<<14) + (((HD)<<4) + pxl)*64 \
                  + wv*16 + ((quad>>1)<<3) + ((quad&1)<<2); \
  *(ushort4*)dst_ = *(const ushort4*)tmp_; }

#define BODY(HD, X, Y) { \
  float bias_[16]; \
  _Pragma("unroll") for (int n2_ = 0; n2_ < 4; ++n2_){ \
    float4 b4_ = *(const float4*)(BIAST + ((((HD)*4 + n2_)*256) + t)*4); \
    bias_[n2_*4+0] = b4_.x; bias_[n2_*4+1] = b4_.y; \
    bias_[n2_*4+2] = b4_.z; bias_[n2_*4+3] = b4_.w; } \
  if ((HD) < 15){ \
    int ns_ = ((HD)+1)&1; \
    LDW(Y, (HD)+1, 1); \
    f32x4 acq_; DOMAT(X, acq_); STQ(acq_, ns_); \
    LDW(X, (HD)+1, 2); \
    f32x4 ack_; DOMAT(Y, ack_); STK(ack_, ns_); \
    int h2_ = ((HD)+2 > 15) ? 15 : (HD)+2; \
    LDW(Y, h2_, 0); \
    f32x4 acv_; DOMAT(X, acv_); STV(acv_, ns_); } \
  ATTEND(HD, bias_); \
  __syncthreads(); }

__global__ __launch_bounds__(256, 3) void k_attn(
    const u16* __restrict__ XT, const u16* __restrict__ WQB,
    const float* __restrict__ BIAST, u16* __restrict__ ATT){
  __shared__ __align__(16) unsigned char smem[34304];
  // xt u16[64][264] @0 (33792B), dead after A-frag hoist. Then union:
  //   set s @ s*12544: qb u16[64][40], kb u16[64][40] @+5120, vbt u16[16][72] @+10240
  //   pb u16[64][72] @25088
  u16* xt = (u16*)smem;
  int t = threadIdx.x;
  int bi = blockIdx.x;
  int b = bi >> 10; int wi = bi & 1023;
  int wv = t >> 6, lane = t & 63, pxl = lane & 15, quad = lane >> 4;
  int tok0 = wv*16 + quad*4;

  bf8 wA[8], wB[8];
  LDW(wA, 0, 0);                       // issue early: hides under staging

  // ---- stage XT window block: 32KB fully contiguous
  const u16* src = XT + ((b*1024 + wi)<<14);
  for (int e = t; e < 2048; e += 256)
    *(uint4*)(xt + (e>>5)*264 + (e&31)*8) = *(const uint4*)(src + e*8);
  __syncthreads();
  // ---- hoist A-frags
  bf8 af[8];
  #pragma unroll
  for (int kc = 0; kc < 8; ++kc)
    af[kc] = *(const bf8*)(xt + (wv*16 + pxl)*264 + kc*32 + quad*8);
  __syncthreads();                      // xt now dead
  // ---- zero filler cols d=16..31 of qb,kb (both sets) for K=32 zero-pad
  for (int e = t; e < 2048; e += 256){
    int cp = e & 7; int row = (e>>3) & 63; int s2 = (e>>9) & 1; int qk = e >> 10;
    *(unsigned int*)(smem + s2*12544 + qk*5120 + row*80 + 32 + cp*4) = 0u;
  }
  bf8 one8;
  #pragma unroll
  for (int j = 0; j < 8; ++j) one8[j] = (__bf16)1.0f;

  // ---- prologue: project head 0 into set 0; ends with q-weights(1) in wB
  {
    LDW(wB, 0, 1);
    f32x4 a0; DOMAT(wA, a0); STQ(a0, 0);
    LDW(wA, 0, 2);
    f32x4 a1; DOMAT(wB, a1); STK(a1, 0);
    LDW(wB, 1, 0);
    f32x4 a2; DOMAT(wA, a2); STV(a2, 0);
  }
  __syncthreads();

  for (int hp = 0; hp < 8; ++hp){
    int hd0 = hp*2;
    BODY(hd0,   wB, wA);
    BODY(hd0+1, wA, wB);
  }
}

// ---------------------------------------------------------------------------
// K3: comb = avgpool_v(attn) + avgpool_h(attn) + local, in-place into LOCB.
// ATT is window-tiled [b][wi][c][tok]; stage uint4 per window-row (16B).
// ---------------------------------------------------------------------------
__global__ __launch_bounds__(256) void k_comb(
    const u16* __restrict__ ATT, u16* __restrict__ LOCB){
  __shared__ float pt[39][256];
  int bi = blockIdx.x;
  int rb = bi & 7; int c = (bi>>3)&255; int b = bi>>11;
  int h0 = rb<<5;
  int t = threadIdx.x;
  const u16* Pb = ATT + (b*1024<<14) + c*64;
  for (int e = t; e < 1248; e += 256){
    int r = e >> 5; int w8 = e & 31;
    int g = h0 - 3 + r;
    int gg = (g == 256) ? 254 : g;
    if ((unsigned)gg < 256u){
      const u16* src = Pb + (((gg>>3)*32 + w8)<<14) + ((gg&7)<<3);
      uint4 q4 = *(const uint4*)src;
      pt[r][w8*8+0] = b2f((u16)(q4.x & 0xffffu));
      pt[r][w8*8+1] = b2f((u16)(q4.x >> 16));
      pt[r][w8*8+2] = b2f((u16)(q4.y & 0xffffu));
      pt[r][w8*8+3] = b2f((u16)(q4.y >> 16));
      pt[r][w8*8+4] = b2f((u16)(q4.z & 0xffffu));
      pt[r][w8*8+5] = b2f((u16)(q4.z >> 16));
      pt[r][w8*8+6] = b2f((u16)(q4.w & 0xffffu));
      pt[r][w8*8+7] = b2f((u16)(q4.w >> 16));
    } else {
      #pragma unroll
      for (int j = 0; j < 8; ++j) pt[r][w8*8+j] = 0.f;
    }
  }
  __syncthreads();
  int w = t;
  float colsum = 0.f;
  #pragma unroll
  for (int k = 0; k < 8; ++k) colsum += pt[k][w];
  u16* O = LOCB + (b*256 + c)*65536 + (h0<<8);
  for (int hr = 0; hr < 32; ++hr){
    const float* prow = pt[hr + 3];
    float s = 0.f;
    #pragma unroll
    for (int j = 0; j < 8; ++j){
      int cc = w - 3 + j;
      float v = 0.f;
      if ((unsigned)cc < 256u) v = prow[cc];
      else if (cc == 256) v = prow[254];
      s += v;
    }
    float res = (colsum + s)*0.125f + b2f(O[(hr<<8) + w]);
    O[(hr<<8) + w] = f2b(res);
    if (hr < 31) colsum += pt[hr+8][w] - pt[hr][w];
  }
}

// ---------------------------------------------------------------------------
// K4: 8x8 depthwise conv, reflect(0,1) pad + zero conv-pad 3 -> DWO (bf16)
// ---------------------------------------------------------------------------
__global__ __launch_bounds__(256) void k_dw(
    const u16* __restrict__ COMB, const float* __restrict__ wdw,
    u16* __restrict__ DWO){
  __shared__ float pt[39][264];
  __shared__ float wl[64];
  int bi = blockIdx.x;
  int rb = bi & 7; int c = (bi>>3)&255; int b = bi>>11;
  int h0 = rb<<5;
  int t = threadIdx.x;
  const u16* P = COMB + (b*256 + c)*65536;
  for (int e = t; e < 10296; e += 256){
    int r = e / 264; int cc = e - r*264;
    int g = h0 - 3 + r;
    int gc = cc - 3;
    int gr  = (g  == 256) ? 254 : g;
    int gcc = (gc == 256) ? 254 : gc;
    float v = 0.f;
    if (((unsigned)gr < 256u) && ((unsigned)gcc < 256u))
      v = b2f(P[(gr<<8) + gcc]);
    pt[r][cc] = v;
  }
  if (t < 64) wl[t] = wdw[(c<<6) + t];
  __syncthreads();
  int w = t;
  for (int hr = 0; hr < 32; ++hr){
    float acc = 0.f;
    #pragma unroll
    for (int i = 0; i < 8; ++i){
      const float* prow = &pt[hr + i][w];
      #pragma unroll
      for (int j = 0; j < 8; ++j)
        acc += wl[(i<<3) + j] * prow[j];
    }
    DWO[(b*256 + c)*65536 + ((h0+hr)<<8) + w] = f2b(acc);
  }
}

// ---------------------------------------------------------------------------
// K5: pointwise 1x1 as implicit GEMM via MFMA (weights bf16 hi+lo).
// ---------------------------------------------------------------------------
__global__ __launch_bounds__(256) void k_pw(
    const u16* __restrict__ DW, const u16* __restrict__ WPB,
    const float* __restrict__ BIASPW, float* __restrict__ OUT){
  __shared__ __align__(16) u16 dt[2][2560];   // [buf][px64 * 40] (k 32 + pad)
  int bi = blockIdx.x;
  int ot = bi & 3; int ptile = bi >> 2;
  int t = threadIdx.x;
  int wv = t >> 6, lane = t & 63, pxl = lane & 15, quad = lane >> 4;
  int n0 = ptile << 6;
  int b = n0 >> 16; int pix0 = n0 & 65535;
  const u16* Dbase = DW + b*16777216 + pix0;
  int spx = t & 63, skl = t >> 6;
  f32x4 acc[4];
  #pragma unroll
  for (int nt = 0; nt < 4; ++nt) acc[nt] = (f32x4){0.f,0.f,0.f,0.f};
  #pragma unroll
  for (int p = 0; p < 8; ++p){
    int k = skl*8 + p;
    dt[0][spx*40 + k] = Dbase[k*65536 + spx];
  }
  __syncthreads();
  const u16* wbase = WPB + (((ot*8)*4 + quad)*64 + wv*16 + pxl)*8;
  for (int c8 = 0; c8 < 8; ++c8){
    int buf = c8 & 1;
    if (c8 < 7){
      #pragma unroll
      for (int p = 0; p < 8; ++p){
        int k = skl*8 + p;
        dt[buf^1][spx*40 + k] = Dbase[((c8+1)*32 + k)*65536 + spx];
      }
    }
    bf8 ah = *(const bf8*)(wbase + c8*2048);
    bf8 al = *(const bf8*)(wbase + 65536 + c8*2048);
    #pragma unroll
    for (int nt = 0; nt < 4; ++nt){
      bf8 bk = *(const bf8*)(&dt[buf][(nt*16 + pxl)*40 + quad*8]);
      acc[nt] = __builtin_amdgcn_mfma_f32_16x16x32_bf16(ah, bk, acc[nt], 0,0,0);
      acc[nt] = __builtin_amdgcn_mfma_f32_16x16x32_bf16(al, bk, acc[nt], 0,0,0);
    }
    __syncthreads();
  }
  int oc = ot*64 + wv*16 + quad*4;
  float bs[4];
  #pragma unroll
  for (int r = 0; r < 4; ++r) bs[r] = BIASPW[oc + r];
  #pragma unroll
  for (int nt = 0; nt < 4; ++nt)
    #pragma unroll
    for (int r = 0; r < 4; ++r)
      OUT[(b*256 + oc + r)*65536 + pix0 + nt*16 + pxl] = acc[nt][r] + bs[r];
}

// ---------------------------------------------------------------------------
extern "C" void kernel_launch(void* const* d_in, const int* in_sizes, int n_in,
                              void* d_out, int out_size, void* d_ws, size_t ws_size,
                              hipStream_t stream){
  const float* x    = (const float*)d_in[0];
  const float* y    = (const float*)d_in[1];
  const float* wqkv = (const float*)d_in[2];
  const float* wl1  = (const float*)d_in[3];
  const float* g1   = (const float*)d_in[4];
  const float* b1   = (const float*)d_in[5];
  const float* m1   = (const float*)d_in[6];
  const float* v1   = (const float*)d_in[7];
  const float* wl2  = (const float*)d_in[8];
  const float* g2   = (const float*)d_in[9];
  const float* b2   = (const float*)d_in[10];
  const float* m2   = (const float*)d_in[11];
  const float* v2   = (const float*)d_in[12];
  const float* wdw  = (const float*)d_in[13];
  const float* gp   = (const float*)d_in[14];
  const float* bp   = (const float*)d_in[15];
  const float* mp   = (const float*)d_in[16];
  const float* vp   = (const float*)d_in[17];
  const float* wpw  = (const float*)d_in[18];
  const float* rpb  = (const float*)d_in[19];

  float* BIASL  = (float*)d_ws;                    // 256 f32
  u16* WPB      = (u16*)(BIASL + 256);             // 131072 u16 (hi+lo)
  float* BIASPW = (float*)(WPB + 131072);          // 256 f32
  u16* W3B   = (u16*)(BIASPW + 256);               // 589824 bf16 (MFMA layout)
  u16* WQB   = W3B + 589824;                       // 196608 bf16 qkv weights
  float* BIAST = (float*)(WQB + 196608);           // 65536 f32 bias table (256KB)
  u16* R1    = (u16*)(BIAST + 65536);              // 33.5M bf16: YT -> XT -> ATT -> DWO
  u16* R2    = R1 + 33554432;                      // 33.5M bf16: local -> comb in place
  float* OUT = (float*)d_out;

  k_prep_w3<<<2304, 256, 0, stream>>>(wl1, wl2, g1, b1, m1, v1, g2, b2, m2, v2, W3B, BIASL);
  k_prep_pw<<<256, 256, 0, stream>>>(wpw, gp, bp, mp, vp, WPB, BIASPW);
  k_prep_wqkv<<<768, 256, 0, stream>>>(wqkv, WQB);
  k_prep_bias<<<64, 256, 0, stream>>>(rpb, BIAST);
  k_prep_yT<<<512, 256, 0, stream>>>(y, R1);
  k_local<<<8192, 256, 0, stream>>>(R1, W3B, BIASL, R2);
  k_prep_xT<<<512, 256, 0, stream>>>(x, R1);                // overwrites dead YT
  k_attn<<<2048, 256, 0, stream>>>(R1, WQB, BIAST, R1);     // ATT over XT in place
  k_comb<<<4096, 256, 0, stream>>>(R1, R2);
  k_dw<<<4096, 256, 0, stream>>>(R2, wdw, R1);              // DWO over dead ATT
  k_pw<<<8192, 256, 0, stream>>>(R1, WPB, BIASPW, OUT);
}

// Round 6
// 1226.712 us; speedup vs baseline: 2.9211x; 1.1088x over previous
//
#include <hip/hip_runtime.h>

typedef unsigned short u16;
typedef __bf16 bf8 __attribute__((ext_vector_type(8)));
typedef float f32x4 __attribute__((ext_vector_type(4)));

// ---------- bf16 helpers for INTERMEDIATE storage (inputs/outputs are fp32) ----------
__device__ __forceinline__ float b2f(u16 u){
  union { unsigned int i; float f; } z; z.i = ((unsigned int)u) << 16; return z.f;
}
__device__ __forceinline__ u16 f2b(float f){
  union { float f; unsigned int i; } z; z.f = f;
  unsigned int lsb = (z.i >> 16) & 1u;
  return (u16)((z.i + 0x7fffu + lsb) >> 16);
}

#define EPSf 1e-5f

// ---------------------------------------------------------------------------
// K0a: fold BN1/BN2 into 3x3 weights (1x1 into center tap) -> W3B bf16 in
// MFMA A-frag layout [ct4][c8 8][tap9][q4][oc64][j8], + BIASL fp32.
// ---------------------------------------------------------------------------
__global__ __launch_bounds__(256) void k_prep_w3(
    const float* __restrict__ w1, const float* __restrict__ w2,
    const float* __restrict__ g1, const float* __restrict__ b1,
    const float* __restrict__ m1, const float* __restrict__ v1,
    const float* __restrict__ g2, const float* __restrict__ b2,
    const float* __restrict__ m2, const float* __restrict__ v2,
    u16* __restrict__ W3B, float* __restrict__ BIASL){
  int e = blockIdx.x*256 + threadIdx.x;       // < 589824
  int c = e / 2304; int r = e - c*2304; int s = r / 9; int tap = r - s*9;
  float inv1 = g1[c] * rsqrtf(v1[c] + EPSf);
  float val = w1[e] * inv1;
  if (tap == 4){
    float inv2 = g2[c] * rsqrtf(v2[c] + EPSf);
    val += w2[c*256 + s] * inv2;
  }
  int ct = c >> 6, oc_l = c & 63;
  int c8 = s >> 5, q = (s >> 3) & 3, j = s & 7;
  W3B[((((ct*8 + c8)*9 + tap)*4 + q)*64 + oc_l)*8 + j] = f2b(val);
  if (e < 256){
    float i1 = g1[e] * rsqrtf(v1[e] + EPSf);
    float i2 = g2[e] * rsqrtf(v2[e] + EPSf);
    BIASL[e] = (b1[e] - m1[e]*i1) + (b2[e] - m2[e]*i2);
  }
}

// ---------------------------------------------------------------------------
// K0b: fold BNp into pointwise weights -> WPB bf16 hi/lo split in MFMA A-frag
// layout, + BIASPW. Parallel: one block per oc, wave+LDS reduce for bias.
// grid 256 x 256
// ---------------------------------------------------------------------------
__global__ __launch_bounds__(256) void k_prep_pw(
    const float* __restrict__ wpw,
    const float* __restrict__ gp, const float* __restrict__ bp,
    const float* __restrict__ mp, const float* __restrict__ vp,
    u16* __restrict__ WPB, float* __restrict__ BIASPW){
  __shared__ float red[4];
  int oc = blockIdx.x; int c = threadIdx.x;
  float iv = gp[c] * rsqrtf(vp[c] + EPSf);
  float beta = bp[c] - mp[c]*iv;
  float w = wpw[oc*256 + c];
  float wf = w * iv;
  u16 hi = f2b(wf);
  u16 lo = f2b(wf - b2f(hi));
  int idx = ((((oc>>6)*8 + (c>>5))*4 + ((c>>3)&3))*64 + (oc&63))*8 + (c&7);
  WPB[idx] = hi;
  WPB[65536 + idx] = lo;
  float s = w * beta;
  #pragma unroll
  for (int off = 1; off < 64; off <<= 1) s += __shfl_xor(s, off);
  if ((c & 63) == 0) red[c>>6] = s;
  __syncthreads();
  if (c == 0) BIASPW[oc] = red[0] + red[1] + red[2] + red[3];
}

// ---------------------------------------------------------------------------
// K0d: convert wqkv fp32 [768][256] -> bf16 same layout.
// ---------------------------------------------------------------------------
__global__ __launch_bounds__(256) void k_prep_wqkv(
    const float* __restrict__ wqkv, u16* __restrict__ WQB){
  int i = blockIdx.x*256 + threadIdx.x;      // < 196608
  WQB[i] = f2b(wqkv[i]);
}

// ---------------------------------------------------------------------------
// K0f: precompute attention bias table in the EXACT per-thread consumption
// layout: BIAST[((hd*4 + nt)*256 + t)*4 + r]. 256KB, L2-resident.
// grid 64 x 256 (blockIdx = hd*4 + nt).
// ---------------------------------------------------------------------------
__global__ __launch_bounds__(256) void k_prep_bias(
    const float* __restrict__ rpb, float* __restrict__ BIAST){
  int hd = blockIdx.x >> 2, nt = blockIdx.x & 3;
  int t = threadIdx.x;
  int wv = t >> 6, lane = t & 63, pxl = lane & 15, quad = lane >> 4;
  int tok0 = wv*16 + quad*4;
  int j = nt*16 + pxl; int rj = j >> 3, cj = j & 7;
  float4 v;
  float* vp_ = (float*)&v;
  #pragma unroll
  for (int r = 0; r < 4; ++r){
    int row = tok0 + r;
    int idx = ((row>>3) - rj + 7)*15 + ((row&7) - cj + 7);
    vp_[r] = rpb[(idx<<4) + hd];
  }
  *(float4*)(BIAST + ((blockIdx.x*256) + t)*4) = v;
}

// ---------------------------------------------------------------------------
// K0c: transpose y (fp32 NCHW) -> YT bf16 NHWC [b][h][w][cin].
// ---------------------------------------------------------------------------
__global__ __launch_bounds__(256) void k_prep_yT(
    const float* __restrict__ y, u16* __restrict__ YT){
  __shared__ u16 ls[32*264];            // [cin32][w 256(+8)]
  int bh = blockIdx.x; int b = bh >> 8; int h = bh & 255;
  int t = threadIdx.x;
  for (int c8 = 0; c8 < 8; ++c8){
    if (c8) __syncthreads();
    for (int ci = 0; ci < 32; ++ci)
      ls[ci*264 + t] = f2b(y[(b*256 + c8*32 + ci)*65536 + h*256 + t]);
    __syncthreads();
    int tq = t & 3, wl = t >> 2;
    for (int wb = 0; wb < 4; ++wb){
      int w = wb*64 + wl;
      u16 tmp[8];
      #pragma unroll
      for (int j = 0; j < 8; ++j) tmp[j] = ls[(tq*8 + j)*264 + w];
      *(uint4*)(YT + ((b*256 + h)*256 + w)*256 + c8*32 + tq*8) = *(const uint4*)tmp;
    }
  }
}

// ---------------------------------------------------------------------------
// K0e: transpose x (fp32 NCHW) -> XT bf16 WINDOW-TILED [b][wi][tok][cin].
// ---------------------------------------------------------------------------
__global__ __launch_bounds__(256) void k_prep_xT(
    const float* __restrict__ x, u16* __restrict__ XT){
  __shared__ u16 ls[32*264];
  int bh = blockIdx.x; int b = bh >> 8; int h = bh & 255;
  int t = threadIdx.x;
  int wrow = (h>>3)<<5, tokr = (h&7)<<3;
  for (int c8 = 0; c8 < 8; ++c8){
    if (c8) __syncthreads();
    for (int ci = 0; ci < 32; ++ci)
      ls[ci*264 + t] = f2b(x[(b*256 + c8*32 + ci)*65536 + h*256 + t]);
    __syncthreads();
    int tq = t & 3, wl = t >> 2;
    for (int wb = 0; wb < 4; ++wb){
      int w = wb*64 + wl;
      u16 tmp[8];
      #pragma unroll
      for (int j = 0; j < 8; ++j) tmp[j] = ls[(tq*8 + j)*264 + w];
      int wi = wrow + (w>>3), tok = tokr + (w&7);
      *(uint4*)(XT + ((b*1024 + wi)*64 + tok)*256 + c8*32 + tq*8) = *(const uint4*)tmp;
    }
  }
}

// ---------------------------------------------------------------------------
// K1: local conv3x3 as implicit GEMM via MFMA 16x16x32 bf16.
// ---------------------------------------------------------------------------
__global__ __launch_bounds__(256) void k_local(
    const u16* __restrict__ YT, const u16* __restrict__ W3B,
    const float* __restrict__ BIASL, u16* __restrict__ LOCB){
  __shared__ __align__(16) u16 wt[18432];   // [tap9][q4][oc64][j8]
  __shared__ __align__(16) u16 yt[8160];    // [row3][col68 (stride 40)][cin32]
  int bi = blockIdx.x;
  int ct = bi & 3, wsg = (bi>>2)&3, h = (bi>>4)&255, b = bi>>12;
  int w0 = wsg << 6;
  int t = threadIdx.x;
  int wv = t >> 6, lane = t & 63, pxl = lane & 15, quad = lane >> 4;
  f32x4 acc0 = {0.f,0.f,0.f,0.f}, acc1 = acc0, acc2 = acc0, acc3 = acc0;
  const u16* wsrc = W3B + ct*8*18432;
  for (int c8 = 0; c8 < 8; ++c8){
    if (c8) __syncthreads();
    const uint4* gs = (const uint4*)(wsrc + c8*18432);
    uint4* wd = (uint4*)wt;
    #pragma unroll
    for (int i = 0; i < 9; ++i) wd[i*256 + t] = gs[i*256 + t];
    for (int e = t; e < 792; e += 256){
      int rc = e >> 2, q = e & 3;
      int row = rc / 66, col = rc - row*66;
      int gh = h - 1 + row, gw = w0 - 1 + col;
      uint4 v = make_uint4(0u,0u,0u,0u);
      if (((unsigned)gh < 256u) && ((unsigned)gw < 256u))
        v = *(const uint4*)(YT + ((b*256 + gh)*256 + gw)*256 + c8*32 + q*8);
      *(uint4*)(yt + (row*68 + col)*40 + q*8) = v;
    }
    __syncthreads();
    #pragma unroll
    for (int tap = 0; tap < 9; ++tap){
      int dr = tap / 3, dc = tap - dr*3;
      bf8 a = *(const bf8*)(wt + ((tap*4 + quad)*64 + wv*16 + pxl)*8);
      int boff = (dr*68 + dc + pxl)*40 + quad*8;
      acc0 = __builtin_amdgcn_mfma_f32_16x16x32_bf16(a, *(const bf8*)(yt + boff       ), acc0, 0,0,0);
      acc1 = __builtin_amdgcn_mfma_f32_16x16x32_bf16(a, *(const bf8*)(yt + boff +  640), acc1, 0,0,0);
      acc2 = __builtin_amdgcn_mfma_f32_16x16x32_bf16(a, *(const bf8*)(yt + boff + 1280), acc2, 0,0,0);
      acc3 = __builtin_amdgcn_mfma_f32_16x16x32_bf16(a, *(const bf8*)(yt + boff + 1920), acc3, 0,0,0);
    }
  }
  int ocb = ct*64 + wv*16 + quad*4;
  float bs[4];
  #pragma unroll
  for (int r = 0; r < 4; ++r) bs[r] = BIASL[ocb + r];
  u16* ob = LOCB + (b*256 + ocb)*65536 + h*256 + w0 + pxl;
  #pragma unroll
  for (int r = 0; r < 4; ++r){
    ob[r*65536 +  0] = f2b(acc0[r] + bs[r]);
    ob[r*65536 + 16] = f2b(acc1[r] + bs[r]);
    ob[r*65536 + 32] = f2b(acc2[r] + bs[r]);
    ob[r*65536 + 48] = f2b(acc3[r] + bs[r]);
  }
}

// ---------------------------------------------------------------------------
// K2: fully-MFMA window attention, TWO windows per block. WQB weight frags and
// BIAST biases are loaded ONCE per head and serve both windows (TA halved per
// window). Single-buffered qkv sets per window + shared wave-private pb;
// 2 barriers/head: {attend A, attend B} | barrier | {project both, banks
// ping-ponged so each LDW hides under 32 MFMAs} | barrier.
// LDS 34304 (setA@0, setB@12544, pb@25088); xt staging unions over the sets.
// VGPR ~190 (afA+afB+wA+wB) -> 8 waves/CU = 2 blocks = 4 windows in flight.
// ---------------------------------------------------------------------------
#define LDW(W, H, MAT) { \
  const u16* bb_ = WQB + ((((MAT)<<8) + ((H)<<4) + pxl)<<8) + (quad<<3); \
  _Pragma("unroll") for (int kc_ = 0; kc_ < 8; ++kc_) W[kc_] = *(const bf8*)(bb_ + kc_*32); }

#define DOMAT(AF, W, ACC) { ACC = (f32x4){0.f,0.f,0.f,0.f}; \
  _Pragma("unroll") for (int kc_ = 0; kc_ < 8; ++kc_) \
    ACC = __builtin_amdgcn_mfma_f32_16x16x32_bf16(AF[kc_], W[kc_], ACC, 0,0,0); }

#define STQ(ACC, SB) { u16* qb_ = (u16*)(smem + (SB)); \
  _Pragma("unroll") for (int r_ = 0; r_ < 4; ++r_) qb_[(tok0+r_)*40 + pxl] = f2b(ACC[r_]*0.25f); }

#define STK(ACC, SB) { u16* kb_ = (u16*)(smem + (SB) + 5120); \
  _Pragma("unroll") for (int r_ = 0; r_ < 4; ++r_) kb_[(tok0+r_)*40 + pxl] = f2b(ACC[r_]); }

#define STV(ACC, SB) { u16* vbt_ = (u16*)(smem + (SB) + 10240); \
  u16 tmp_[4]; _Pragma("unroll") for (int r_ = 0; r_ < 4; ++r_) tmp_[r_] = f2b(ACC[r_]); \
  *(ushort4*)(vbt_ + pxl*72 + tok0) = *(const ushort4*)tmp_; }

#define ATTEND(SB, WI, HD, BIAS) { \
  u16* qb_ = (u16*)(smem + (SB)); \
  u16* kb_ = (u16*)(smem + (SB) + 5120); \
  u16* vbt_ = (u16*)(smem + (SB) + 10240); \
  u16* pb_ = (u16*)(smem + 25088); \
  bf8 aq_ = *(const bf8*)(qb_ + (wv*16 + pxl)*40 + quad*8); \
  f32x4 sc_[4]; \
  _Pragma("unroll") for (int nt_ = 0; nt_ < 4; ++nt_){ \
    bf8 bk_ = *(const bf8*)(kb_ + (nt_*16 + pxl)*40 + quad*8); \
    f32x4 z_ = {0.f,0.f,0.f,0.f}; \
    sc_[nt_] = __builtin_amdgcn_mfma_f32_16x16x32_bf16(aq_, bk_, z_, 0,0,0); } \
  _Pragma("unroll") for (int nt_ = 0; nt_ < 4; ++nt_) \
    _Pragma("unroll") for (int r_ = 0; r_ < 4; ++r_){ \
      float e_ = __expf(sc_[nt_][r_] + BIAS[nt_*4+r_]); \
      pb_[(tok0 + r_)*72 + nt_*16 + pxl] = f2b(e_); } \
  const u16* prow_ = pb_ + (wv*16 + pxl)*72 + quad*8; \
  const u16* vrow_ = vbt_ + pxl*72 + quad*8; \
  bf8 pa0_ = *(const bf8*)(prow_); \
  bf8 pa1_ = *(const bf8*)(prow_ + 32); \
  bf8 vb0_ = *(const bf8*)(vrow_); \
  bf8 vb1_ = *(const bf8*)(vrow_ + 32); \
  f32x4 o_ = {0.f,0.f,0.f,0.f}; f32x4 rs_ = {0.f,0.f,0.f,0.f}; \
  o_ = __builtin_amdgcn_mfma_f32_16x16x32_bf16(pa0_, vb0_, o_, 0,0,0); \
  o_ = __builtin_amdgcn_mfma_f32_16x16x32_bf16(pa1_, vb1_, o_, 0,0,0); \
  rs_ = __builtin_amdgcn_mfma_f32_16x16x32_bf16(pa0_, one8, rs_, 0,0,0); \
  rs_ = __builtin_amdgcn_mfma_f32_16x16x32_bf16(pa1_, one8, rs_, 0,0,0); \
  u16 tmp_[4]; \
  _Pragma("unroll") for (int r_ = 0; r_ < 4; ++r_) \
    tmp_[r_] = f2b(o_[r_] * __builtin_amdgcn_rcpf(rs_[r_])); \
  u16* dst_ = ATT + ((b*1024 + (WI))<<14) + (((HD)<<4) + pxl)*64 \
                  + wv*16 + ((quad>>1)<<3) + ((quad&1)<<2); \
  *(ushort4*)dst_ = *(const ushort4*)tmp_; }

// X = bank holding q(HD+1) at entry; Y = dead bank at entry.
#define BODY2(HD, X, Y) { \
  float bias_[16]; \
  _Pragma("unroll") for (int n2_ = 0; n2_ < 4; ++n2_){ \
    float4 b4_ = *(const float4*)(BIAST + ((((HD)*4 + n2_)*256) + t)*4); \
    bias_[n2_*4+0] = b4_.x; bias_[n2_*4+1] = b4_.y; \
    bias_[n2_*4+2] = b4_.z; bias_[n2_*4+3] = b4_.w; } \
  if ((HD) < 15) LDW(Y, (HD)+1, 1);            /* k-weights hide under attends */ \
  ATTEND(0,     wiA, HD, bias_); \
  ATTEND(12544, wiB, HD, bias_); \
  __syncthreads(); \
  if ((HD) < 15){ \
    f32x4 ac_; \
    DOMAT(afA, X, ac_); STQ(ac_, 0); \
    DOMAT(afB, X, ac_); STQ(ac_, 12544); \
    LDW(X, (HD)+1, 2);                          /* v-weights hide under k-proj */ \
    DOMAT(afA, Y, ac_); STK(ac_, 0); \
    DOMAT(afB, Y, ac_); STK(ac_, 12544); \
    { int h2_ = ((HD)+2 > 15) ? 15 : (HD)+2; LDW(Y, h2_, 0); } /* next q under v-proj */ \
    DOMAT(afA, X, ac_); STV(ac_, 0); \
    DOMAT(afB, X, ac_); STV(ac_, 12544); \
    __syncthreads(); \
  } }

__global__ __launch_bounds__(256, 2) void k_attn(
    const u16* __restrict__ XT, const u16* __restrict__ WQB,
    const float* __restrict__ BIAST, u16* __restrict__ ATT){
  __shared__ __align__(16) unsigned char smem[34304];
  // xt u16[64][264] @0 (33792B) during prologue staging only. Then:
  //   setA @0: qb[64][40], kb @+5120, vbt[16][72] @+10240   (12544B)
  //   setB @12544: same layout                               (12544B)
  //   pb  @25088: u16[64][72]                                (9216B)
  u16* xt = (u16*)smem;
  int t = threadIdx.x;
  int bi = blockIdx.x;
  int b = bi >> 9; int widx = bi & 511;
  int wiA = widx*2, wiB = wiA + 1;
  int wv = t >> 6, lane = t & 63, pxl = lane & 15, quad = lane >> 4;
  int tok0 = wv*16 + quad*4;

  bf8 wA[8], wB[8];
  LDW(wA, 0, 0);                       // q(0), hides under staging

  // ---- stage window A (32KB contiguous), hoist afA
  bf8 afA[8], afB[8];
  {
    const u16* srcA = XT + ((b*1024 + wiA)<<14);
    for (int e = t; e < 2048; e += 256)
      *(uint4*)(xt + (e>>5)*264 + (e&31)*8) = *(const uint4*)(srcA + e*8);
  }
  __syncthreads();
  #pragma unroll
  for (int kc = 0; kc < 8; ++kc)
    afA[kc] = *(const bf8*)(xt + (wv*16 + pxl)*264 + kc*32 + quad*8);
  __syncthreads();
  // ---- stage window B, hoist afB
  {
    const u16* srcB = XT + ((b*1024 + wiB)<<14);
    for (int e = t; e < 2048; e += 256)
      *(uint4*)(xt + (e>>5)*264 + (e&31)*8) = *(const uint4*)(srcB + e*8);
  }
  __syncthreads();
  #pragma unroll
  for (int kc = 0; kc < 8; ++kc)
    afB[kc] = *(const bf8*)(xt + (wv*16 + pxl)*264 + kc*32 + quad*8);
  __syncthreads();                      // xt now dead
  // ---- zero filler cols d=16..31 of qb,kb (both sets) for K=32 zero-pad
  for (int e = t; e < 2048; e += 256){
    int cp = e & 7; int row = (e>>3) & 63; int s2 = (e>>9) & 1; int qk = e >> 10;
    *(unsigned int*)(smem + s2*12544 + qk*5120 + row*80 + 32 + cp*4) = 0u;
  }
  bf8 one8;
  #pragma unroll
  for (int j = 0; j < 8; ++j) one8[j] = (__bf16)1.0f;

  // ---- prologue: project head 0 into both sets; ends with q(1) in wB
  {
    f32x4 a_;
    LDW(wB, 0, 1);
    DOMAT(afA, wA, a_); STQ(a_, 0);
    DOMAT(afB, wA, a_); STQ(a_, 12544);
    LDW(wA, 0, 2);
    DOMAT(afA, wB, a_); STK(a_, 0);
    DOMAT(afB, wB, a_); STK(a_, 12544);
    LDW(wB, 1, 0);
    DOMAT(afA, wA, a_); STV(a_, 0);
    DOMAT(afB, wA, a_); STV(a_, 12544);
  }
  __syncthreads();

  for (int hp = 0; hp < 8; ++hp){
    int hd0 = hp*2;
    BODY2(hd0,   wB, wA);
    BODY2(hd0+1, wA, wB);
  }
}

// ---------------------------------------------------------------------------
// K3: comb = avgpool_v(attn) + avgpool_h(attn) + local, in-place into LOCB.
// ATT is window-tiled [b][wi][c][tok]; stage uint4 per window-row (16B).
// ---------------------------------------------------------------------------
__global__ __launch_bounds__(256) void k_comb(
    const u16* __restrict__ ATT, u16* __restrict__ LOCB){
  __shared__ float pt[39][256];
  int bi = blockIdx.x;
  int rb = bi & 7; int c = (bi>>3)&255; int b = bi>>11;
  int h0 = rb<<5;
  int t = threadIdx.x;
  const u16* Pb = ATT + (b*1024<<14) + c*64;
  for (int e = t; e < 1248; e += 256){
    int r = e >> 5; int w8 = e & 31;
    int g = h0 - 3 + r;
    int gg = (g == 256) ? 254 : g;
    if ((unsigned)gg < 256u){
      const u16* src = Pb + (((gg>>3)*32 + w8)<<14) + ((gg&7)<<3);
      uint4 q4 = *(const uint4*)src;
      pt[r][w8*8+0] = b2f((u16)(q4.x & 0xffffu));
      pt[r][w8*8+1] = b2f((u16)(q4.x >> 16));
      pt[r][w8*8+2] = b2f((u16)(q4.y & 0xffffu));
      pt[r][w8*8+3] = b2f((u16)(q4.y >> 16));
      pt[r][w8*8+4] = b2f((u16)(q4.z & 0xffffu));
      pt[r][w8*8+5] = b2f((u16)(q4.z >> 16));
      pt[r][w8*8+6] = b2f((u16)(q4.w & 0xffffu));
      pt[r][w8*8+7] = b2f((u16)(q4.w >> 16));
    } else {
      #pragma unroll
      for (int j = 0; j < 8; ++j) pt[r][w8*8+j] = 0.f;
    }
  }
  __syncthreads();
  int w = t;
  float colsum = 0.f;
  #pragma unroll
  for (int k = 0; k < 8; ++k) colsum += pt[k][w];
  u16* O = LOCB + (b*256 + c)*65536 + (h0<<8);
  for (int hr = 0; hr < 32; ++hr){
    const float* prow = pt[hr + 3];
    float s = 0.f;
    #pragma unroll
    for (int j = 0; j < 8; ++j){
      int cc = w - 3 + j;
      float v = 0.f;
      if ((unsigned)cc < 256u) v = prow[cc];
      else if (cc == 256) v = prow[254];
      s += v;
    }
    float res = (colsum + s)*0.125f + b2f(O[(hr<<8) + w]);
    O[(hr<<8) + w] = f2b(res);
    if (hr < 31) colsum += pt[hr+8][w] - pt[hr][w];
  }
}

// ---------------------------------------------------------------------------
// K4: 8x8 depthwise conv, reflect(0,1) pad + zero conv-pad 3 -> DWO (bf16)
// ---------------------------------------------------------------------------
__global__ __launch_bounds__(256) void k_dw(
    const u16* __restrict__ COMB, const float* __restrict__ wdw,
    u16* __restrict__ DWO){
  __shared__ float pt[39][264];
  __shared__ float wl[64];
  int bi = blockIdx.x;
  int rb = bi & 7; int c = (bi>>3)&255; int b = bi>>11;
  int h0 = rb<<5;
  int t = threadIdx.x;
  const u16* P = COMB + (b*256 + c)*65536;
  for (int e = t; e < 10296; e += 256){
    int r = e / 264; int cc = e - r*264;
    int g = h0 - 3 + r;
    int gc = cc - 3;
    int gr  = (g  == 256) ? 254 : g;
    int gcc = (gc == 256) ? 254 : gc;
    float v = 0.f;
    if (((unsigned)gr < 256u) && ((unsigned)gcc < 256u))
      v = b2f(P[(gr<<8) + gcc]);
    pt[r][cc] = v;
  }
  if (t < 64) wl[t] = wdw[(c<<6) + t];
  __syncthreads();
  int w = t;
  for (int hr = 0; hr < 32; ++hr){
    float acc = 0.f;
    #pragma unroll
    for (int i = 0; i < 8; ++i){
      const float* prow = &pt[hr + i][w];
      #pragma unroll
      for (int j = 0; j < 8; ++j)
        acc += wl[(i<<3) + j] * prow[j];
    }
    DWO[(b*256 + c)*65536 + ((h0+hr)<<8) + w] = f2b(acc);
  }
}

// ---------------------------------------------------------------------------
// K5: pointwise 1x1 as implicit GEMM via MFMA (weights bf16 hi+lo).
// ---------------------------------------------------------------------------
__global__ __launch_bounds__(256) void k_pw(
    const u16* __restrict__ DW, const u16* __restrict__ WPB,
    const float* __restrict__ BIASPW, float* __restrict__ OUT){
  __shared__ __align__(16) u16 dt[2][2560];   // [buf][px64 * 40] (k 32 + pad)
  int bi = blockIdx.x;
  int ot = bi & 3; int ptile = bi >> 2;
  int t = threadIdx.x;
  int wv = t >> 6, lane = t & 63, pxl = lane & 15, quad = lane >> 4;
  int n0 = ptile << 6;
  int b = n0 >> 16; int pix0 = n0 & 65535;
  const u16* Dbase = DW + b*16777216 + pix0;
  int spx = t & 63, skl = t >> 6;
  f32x4 acc[4];
  #pragma unroll
  for (int nt = 0; nt < 4; ++nt) acc[nt] = (f32x4){0.f,0.f,0.f,0.f};
  #pragma unroll
  for (int p = 0; p < 8; ++p){
    int k = skl*8 + p;
    dt[0][spx*40 + k] = Dbase[k*65536 + spx];
  }
  __syncthreads();
  const u16* wbase = WPB + (((ot*8)*4 + quad)*64 + wv*16 + pxl)*8;
  for (int c8 = 0; c8 < 8; ++c8){
    int buf = c8 & 1;
    if (c8 < 7){
      #pragma unroll
      for (int p = 0; p < 8; ++p){
        int k = skl*8 + p;
        dt[buf^1][spx*40 + k] = Dbase[((c8+1)*32 + k)*65536 + spx];
      }
    }
    bf8 ah = *(const bf8*)(wbase + c8*2048);
    bf8 al = *(const bf8*)(wbase + 65536 + c8*2048);
    #pragma unroll
    for (int nt = 0; nt < 4; ++nt){
      bf8 bk = *(const bf8*)(&dt[buf][(nt*16 + pxl)*40 + quad*8]);
      acc[nt] = __builtin_amdgcn_mfma_f32_16x16x32_bf16(ah, bk, acc[nt], 0,0,0);
      acc[nt] = __builtin_amdgcn_mfma_f32_16x16x32_bf16(al, bk, acc[nt], 0,0,0);
    }
    __syncthreads();
  }
  int oc = ot*64 + wv*16 + quad*4;
  float bs[4];
  #pragma unroll
  for (int r = 0; r < 4; ++r) bs[r] = BIASPW[oc + r];
  #pragma unroll
  for (int nt = 0; nt < 4; ++nt)
    #pragma unroll
    for (int r = 0; r < 4; ++r)
      OUT[(b*256 + oc + r)*65536 + pix0 + nt*16 + pxl] = acc[nt][r] + bs[r];
}

// ---------------------------------------------------------------------------
extern "C" void kernel_launch(void* const* d_in, const int* in_sizes, int n_in,
                              void* d_out, int out_size, void* d_ws, size_t ws_size,
                              hipStream_t stream){
  const float* x    = (const float*)d_in[0];
  const float* y    = (const float*)d_in[1];
  const float* wqkv = (const float*)d_in[2];
  const float* wl1  = (const float*)d_in[3];
  const float* g1   = (const float*)d_in[4];
  const float* b1   = (const float*)d_in[5];
  const float* m1   = (const float*)d_in[6];
  const float* v1   = (const float*)d_in[7];
  const float* wl2  = (const float*)d_in[8];
  const float* g2   = (const float*)d_in[9];
  const float* b2   = (const float*)d_in[10];
  const float* m2   = (const float*)d_in[11];
  const float* v2   = (const float*)d_in[12];
  const float* wdw  = (const float*)d_in[13];
  const float* gp   = (const float*)d_in[14];
  const float* bp   = (const float*)d_in[15];
  const float* mp   = (const float*)d_in[16];
  const float* vp   = (const float*)d_in[17];
  const float* wpw  = (const float*)d_in[18];
  const float* rpb  = (const float*)d_in[19];

  float* BIASL  = (float*)d_ws;                    // 256 f32
  u16* WPB      = (u16*)(BIASL + 256);             // 131072 u16 (hi+lo)
  float* BIASPW = (float*)(WPB + 131072);          // 256 f32
  u16* W3B   = (u16*)(BIASPW + 256);               // 589824 bf16 (MFMA layout)
  u16* WQB   = W3B + 589824;                       // 196608 bf16 qkv weights
  float* BIAST = (float*)(WQB + 196608);           // 65536 f32 bias table (256KB)
  u16* R1    = (u16*)(BIAST + 65536);              // 33.5M bf16: YT -> XT -> ATT -> DWO
  u16* R2    = R1 + 33554432;                      // 33.5M bf16: local -> comb in place
  float* OUT = (float*)d_out;

  k_prep_w3<<<2304, 256, 0, stream>>>(wl1, wl2, g1, b1, m1, v1, g2, b2, m2, v2, W3B, BIASL);
  k_prep_pw<<<256, 256, 0, stream>>>(wpw, gp, bp, mp, vp, WPB, BIASPW);
  k_prep_wqkv<<<768, 256, 0, stream>>>(wqkv, WQB);
  k_prep_bias<<<64, 256, 0, stream>>>(rpb, BIAST);
  k_prep_yT<<<512, 256, 0, stream>>>(y, R1);
  k_local<<<8192, 256, 0, stream>>>(R1, W3B, BIASL, R2);
  k_prep_xT<<<512, 256, 0, stream>>>(x, R1);                // overwrites dead YT
  k_attn<<<1024, 256, 0, stream>>>(R1, WQB, BIAST, R1);     // ATT over XT in place
  k_comb<<<4096, 256, 0, stream>>>(R1, R2);
  k_dw<<<4096, 256, 0, stream>>>(R2, wdw, R1);              // DWO over dead ATT
  k_pw<<<8192, 256, 0, stream>>>(R1, WPB, BIASPW, OUT);
}